// Round 1
// 1041.222 us; speedup vs baseline: 1.1417x; 1.1417x over previous
//
#include <hip/hip_runtime.h>
#include <hip/hip_bf16.h>
#include <math.h>

// Problem constants (fixed by the reference)
#define GN 100000   // nodes
#define GE 1200000  // edges
#define GB 128      // graphs
#define GF 92       // raw features
#define GD 64       // hidden dim
#define GL 3        // CGConv layers
#define GZ 129      // 2*D+1

// round-to-nearest-even fp32 -> bf16 (returned in low 16 bits)
__device__ __forceinline__ unsigned int f2bf_rne(float x)
{
    unsigned int u = __float_as_uint(x);
    u += 0x7fffu + ((u >> 16) & 1u);
    return u >> 16;
}

// ---------------------------------------------------------------------------
// Fused pre-MLP (3 layers) + P0, lane = node.
// R11 rewrite: weights staged in LDS (32 KiB buffer reused per phase),
// rolled c-loops with acc[64] register blocking (no runtime-indexed register
// arrays -> no scratch), h row ping-pongs through this thread's own global
// slot (L1/L2 resident). Replaces ~180 KB of fully-unrolled code + scalar-K$
// weight streams (VALUBusy was 20%, occupancy 15%).
// ---------------------------------------------------------------------------
__global__ __launch_bounds__(256, 2) void premlp_kernel(
    const float* __restrict__ X,
    const float* __restrict__ W0, const float* __restrict__ b0,
    const float* __restrict__ W1, const float* __restrict__ b1,
    const float* __restrict__ W2, const float* __restrict__ b2,
    const float* __restrict__ WfN, const float* __restrict__ WsN,
    float* __restrict__ hout, unsigned int* __restrict__ Pout, int N)
{
    __shared__ __align__(16) float Wl[8192];   // 32 KiB: W0 | W1 | W2 | (WfN,WsN)
    const int tid = threadIdx.x;
    const int n = blockIdx.x * 256 + tid;
    const int nn = (n < N) ? n : (N - 1);   // clamp so inactive lanes read safely
    const bool act = (n < N);

    float acc[64];

    // ---------------- stage W0 (92x64 = 1472 float4) ----------------
    {
        const float4* __restrict__ s4 = (const float4*)W0;
        float4* __restrict__ d4 = (float4*)Wl;
        for (int i = tid; i < 1472; i += 256) d4[i] = s4[i];
    }
    __syncthreads();

    // ---------------- layer 0: K=92 ----------------
#pragma unroll
    for (int j = 0; j < 64; ++j) acc[j] = b0[j];
    {
        const float4* __restrict__ row4 = (const float4*)(X + (size_t)nn * GF);
#pragma unroll 2
        for (int c = 0; c < 23; ++c) {
            float4 v = row4[c];
            const float* __restrict__ w = Wl + c * 256;
#pragma unroll
            for (int j = 0; j < 64; ++j) {
                acc[j] = fmaf(v.x, w[j], acc[j]);
                acc[j] = fmaf(v.y, w[64 + j], acc[j]);
                acc[j] = fmaf(v.z, w[128 + j], acc[j]);
                acc[j] = fmaf(v.w, w[192 + j], acc[j]);
            }
        }
    }
    if (act) {
        float4* __restrict__ op = (float4*)(hout + (size_t)n * 64);
#pragma unroll
        for (int q = 0; q < 16; ++q)
            op[q] = make_float4(fmaxf(acc[q * 4], 0.f), fmaxf(acc[q * 4 + 1], 0.f),
                                fmaxf(acc[q * 4 + 2], 0.f), fmaxf(acc[q * 4 + 3], 0.f));
    }

    // ---------------- stage W1 ----------------
    __syncthreads();
    {
        const float4* __restrict__ s4 = (const float4*)W1;
        float4* __restrict__ d4 = (float4*)Wl;
        for (int i = tid; i < 1024; i += 256) d4[i] = s4[i];
    }
    __syncthreads();

    // ---------------- layer 1 ----------------
#pragma unroll
    for (int j = 0; j < 64; ++j) acc[j] = b1[j];
    {
        const float4* __restrict__ row4 = (const float4*)(hout + (size_t)nn * 64);
#pragma unroll 2
        for (int c = 0; c < 16; ++c) {
            float4 v = row4[c];
            const float* __restrict__ w = Wl + c * 256;
#pragma unroll
            for (int j = 0; j < 64; ++j) {
                acc[j] = fmaf(v.x, w[j], acc[j]);
                acc[j] = fmaf(v.y, w[64 + j], acc[j]);
                acc[j] = fmaf(v.z, w[128 + j], acc[j]);
                acc[j] = fmaf(v.w, w[192 + j], acc[j]);
            }
        }
    }
    if (act) {
        float4* __restrict__ op = (float4*)(hout + (size_t)n * 64);
#pragma unroll
        for (int q = 0; q < 16; ++q)
            op[q] = make_float4(fmaxf(acc[q * 4], 0.f), fmaxf(acc[q * 4 + 1], 0.f),
                                fmaxf(acc[q * 4 + 2], 0.f), fmaxf(acc[q * 4 + 3], 0.f));
    }

    // ---------------- stage W2 ----------------
    __syncthreads();
    {
        const float4* __restrict__ s4 = (const float4*)W2;
        float4* __restrict__ d4 = (float4*)Wl;
        for (int i = tid; i < 1024; i += 256) d4[i] = s4[i];
    }
    __syncthreads();

    // ---------------- layer 2 ----------------
#pragma unroll
    for (int j = 0; j < 64; ++j) acc[j] = b2[j];
    {
        const float4* __restrict__ row4 = (const float4*)(hout + (size_t)nn * 64);
#pragma unroll 2
        for (int c = 0; c < 16; ++c) {
            float4 v = row4[c];
            const float* __restrict__ w = Wl + c * 256;
#pragma unroll
            for (int j = 0; j < 64; ++j) {
                acc[j] = fmaf(v.x, w[j], acc[j]);
                acc[j] = fmaf(v.y, w[64 + j], acc[j]);
                acc[j] = fmaf(v.z, w[128 + j], acc[j]);
                acc[j] = fmaf(v.w, w[192 + j], acc[j]);
            }
        }
    }
    if (act) {
        float4* __restrict__ op = (float4*)(hout + (size_t)n * 64);
#pragma unroll
        for (int q = 0; q < 16; ++q)
            op[q] = make_float4(fmaxf(acc[q * 4], 0.f), fmaxf(acc[q * 4 + 1], 0.f),
                                fmaxf(acc[q * 4 + 2], 0.f), fmaxf(acc[q * 4 + 3], 0.f));
    }

    // ---------------- stage WfN, WsN (src-half rows of layer-0 gates) ----------------
    __syncthreads();
    {
        const float4* __restrict__ s4 = (const float4*)WfN;
        const float4* __restrict__ t4 = (const float4*)WsN;
        float4* __restrict__ d4 = (float4*)Wl;
        for (int i = tid; i < 1024; i += 256) {
            d4[i] = s4[i];
            d4[1024 + i] = t4[i];
        }
    }
    __syncthreads();

    // ---------------- P0 projection, packed bf16 ----------------
    float accS[64];
#pragma unroll
    for (int j = 0; j < 64; ++j) { acc[j] = 0.f; accS[j] = 0.f; }
    {
        const float4* __restrict__ row4 = (const float4*)(hout + (size_t)nn * 64);
#pragma unroll 2
        for (int c = 0; c < 16; ++c) {
            float4 v = row4[c];
            const float* __restrict__ wf = Wl + c * 256;
            const float* __restrict__ ws = Wl + 4096 + c * 256;
#pragma unroll
            for (int j = 0; j < 64; ++j) {
                acc[j] = fmaf(v.x, wf[j], acc[j]);
                acc[j] = fmaf(v.y, wf[64 + j], acc[j]);
                acc[j] = fmaf(v.z, wf[128 + j], acc[j]);
                acc[j] = fmaf(v.w, wf[192 + j], acc[j]);
                accS[j] = fmaf(v.x, ws[j], accS[j]);
                accS[j] = fmaf(v.y, ws[64 + j], accS[j]);
                accS[j] = fmaf(v.z, ws[128 + j], accS[j]);
                accS[j] = fmaf(v.w, ws[192 + j], accS[j]);
            }
        }
    }
    if (act) {
        uint4* __restrict__ pp = (uint4*)(Pout + (size_t)n * 64);
#pragma unroll
        for (int q = 0; q < 16; ++q) {
            uint4 pk;
            pk.x = f2bf_rne(acc[q * 4])     | (f2bf_rne(accS[q * 4]) << 16);
            pk.y = f2bf_rne(acc[q * 4 + 1]) | (f2bf_rne(accS[q * 4 + 1]) << 16);
            pk.z = f2bf_rne(acc[q * 4 + 2]) | (f2bf_rne(accS[q * 4 + 2]) << 16);
            pk.w = f2bf_rne(acc[q * 4 + 3]) | (f2bf_rne(accS[q * 4 + 3]) << 16);
            pp[q] = pk;
        }
    }
}

// ---------------------------------------------------------------------------
// P projection (src half of both gates), lane = node, packed bf16 output.
// R11 rewrite: same LDS-staged-weights + acc[64] structure as premlp.
// ---------------------------------------------------------------------------
__global__ __launch_bounds__(256, 2) void pj_kernel(
    const float* __restrict__ h,
    const float* __restrict__ Wf, const float* __restrict__ Ws,
    unsigned int* __restrict__ P, int N)
{
    __shared__ __align__(16) float Wl[8192];   // Wf rows 64..127 | Ws rows 64..127
    const int tid = threadIdx.x;
    const int n = blockIdx.x * 256 + tid;
    const int nn = (n < N) ? n : (N - 1);

    {
        const float4* __restrict__ s4 = (const float4*)(Wf + 64 * 64);
        const float4* __restrict__ t4 = (const float4*)(Ws + 64 * 64);
        float4* __restrict__ d4 = (float4*)Wl;
        for (int i = tid; i < 1024; i += 256) {
            d4[i] = s4[i];
            d4[1024 + i] = t4[i];
        }
    }
    __syncthreads();

    float aF[64], aS[64];
#pragma unroll
    for (int j = 0; j < 64; ++j) { aF[j] = 0.f; aS[j] = 0.f; }
    {
        const float4* __restrict__ row4 = (const float4*)(h + (size_t)nn * 64);
#pragma unroll 2
        for (int c = 0; c < 16; ++c) {
            float4 v = row4[c];
            const float* __restrict__ wf = Wl + c * 256;
            const float* __restrict__ ws = Wl + 4096 + c * 256;
#pragma unroll
            for (int j = 0; j < 64; ++j) {
                aF[j] = fmaf(v.x, wf[j], aF[j]);
                aF[j] = fmaf(v.y, wf[64 + j], aF[j]);
                aF[j] = fmaf(v.z, wf[128 + j], aF[j]);
                aF[j] = fmaf(v.w, wf[192 + j], aF[j]);
                aS[j] = fmaf(v.x, ws[j], aS[j]);
                aS[j] = fmaf(v.y, ws[64 + j], aS[j]);
                aS[j] = fmaf(v.z, ws[128 + j], aS[j]);
                aS[j] = fmaf(v.w, ws[192 + j], aS[j]);
            }
        }
    }
    if (n < N) {
        uint4* __restrict__ pp = (uint4*)(P + (size_t)n * 64);
#pragma unroll
        for (int q = 0; q < 16; ++q) {
            uint4 pk;
            pk.x = f2bf_rne(aF[q * 4])     | (f2bf_rne(aS[q * 4]) << 16);
            pk.y = f2bf_rne(aF[q * 4 + 1]) | (f2bf_rne(aS[q * 4 + 1]) << 16);
            pk.z = f2bf_rne(aF[q * 4 + 2]) | (f2bf_rne(aS[q * 4 + 2]) << 16);
            pk.w = f2bf_rne(aF[q * 4 + 3]) | (f2bf_rne(aS[q * 4 + 3]) << 16);
            pp[q] = pk;
        }
    }
}

// ---------------------------------------------------------------------------
// In-degree histogram (int)
// ---------------------------------------------------------------------------
__global__ __launch_bounds__(256) void deg_kernel(
    const int* __restrict__ dst, int* __restrict__ deg, int E)
{
    int e = blockIdx.x * blockDim.x + threadIdx.x;
    if (e < E) atomicAdd(&deg[dst[e]], 1);
}

// ---------------------------------------------------------------------------
// Three-phase exclusive scan over deg -> rowptr, cursor
// ---------------------------------------------------------------------------
__global__ __launch_bounds__(1024) void scanA_kernel(
    const int* __restrict__ deg, int* __restrict__ iscan,
    int* __restrict__ bsum, int N)
{
    __shared__ int lds[1024];
    int tid = threadIdx.x;
    int gid = blockIdx.x * 1024 + tid;
    int v = (gid < N) ? deg[gid] : 0;
    lds[tid] = v; __syncthreads();
    for (int off = 1; off < 1024; off <<= 1) {
        int t = (tid >= off) ? lds[tid - off] : 0;
        __syncthreads();
        lds[tid] += t;
        __syncthreads();
    }
    if (gid < N) iscan[gid] = lds[tid];
    if (tid == 1023) bsum[blockIdx.x] = lds[1023];
}

__global__ __launch_bounds__(128) void scanB_kernel(
    const int* __restrict__ bsum, int* __restrict__ boff, int nb)
{
    __shared__ int lds[128];
    int t = threadIdx.x;
    int v = (t < nb) ? bsum[t] : 0;
    lds[t] = v; __syncthreads();
    for (int off = 1; off < 128; off <<= 1) {
        int u = (t >= off) ? lds[t - off] : 0;
        __syncthreads();
        lds[t] += u;
        __syncthreads();
    }
    if (t < nb) boff[t] = lds[t] - v;  // exclusive
}

__global__ __launch_bounds__(256) void scanC_kernel(
    const int* __restrict__ iscan, const int* __restrict__ boff,
    const int* __restrict__ deg,
    int* __restrict__ rowptr, int* __restrict__ cursor, int N)
{
    int i = blockIdx.x * blockDim.x + threadIdx.x;
    if (i >= N) return;
    int incl = iscan[i] + boff[i >> 10];
    rowptr[i + 1] = incl;
    cursor[i] = incl - deg[i];
    if (i == 0) rowptr[0] = 0;
}

// ---------------------------------------------------------------------------
// Edge scatter into CSR order, packed (src, ea) int2
// ---------------------------------------------------------------------------
__global__ __launch_bounds__(256) void escatter_kernel(
    const int* __restrict__ src, const int* __restrict__ dst,
    const float* __restrict__ ea, int* __restrict__ cursor,
    int2* __restrict__ e_se, int E)
{
    int e = blockIdx.x * blockDim.x + threadIdx.x;
    if (e >= E) return;
    int pos = atomicAdd(&cursor[dst[e]], 1);
    e_se[pos] = make_int2(src[e], __float_as_int(ea[e]));
}

// ---------------------------------------------------------------------------
// CGConv edge pass (measured-best plain form: VGPR 36, occ 66%, 201us).
// One wave per node, lane = dim.
// ---------------------------------------------------------------------------
__global__ __launch_bounds__(256) void edge_kernel(
    const float* __restrict__ h, const int* __restrict__ rowptr,
    const int2* __restrict__ e_se,
    const unsigned int* __restrict__ P,
    const float* __restrict__ Wf, const float* __restrict__ bfv,
    const float* __restrict__ Ws, const float* __restrict__ bsv,
    float* __restrict__ hout)
{
    int n = blockIdx.x * 4 + (threadIdx.x >> 6);   // grid exactly covers GN
    int d = threadIdx.x & 63;

    // inline dst-projection (wave-uniform float4 broadcast loads)
    const float4* __restrict__ row4 = (const float4*)(h + (size_t)n * 64);
    float qf = bfv[d], qs = bsv[d];
#pragma unroll
    for (int c = 0; c < 16; ++c) {
        float4 v = row4[c];
#pragma unroll
        for (int i = 0; i < 4; ++i) {
            float hk = (i == 0) ? v.x : (i == 1) ? v.y : (i == 2) ? v.z : v.w;
            qf = fmaf(hk, Wf[(c * 4 + i) * 64 + d], qf);
            qs = fmaf(hk, Ws[(c * 4 + i) * 64 + d], qs);
        }
    }
    float wf = Wf[128 * 64 + d];
    float ws = Ws[128 * 64 + d];

    int rb = rowptr[n], re = rowptr[n + 1];
    float agg = 0.f;
#pragma unroll 8
    for (int p = rb; p < re; ++p) {
        int2 se = e_se[p];         // wave-uniform 8B load
        int s = se.x;
        float ea = __int_as_float(se.y);
        unsigned int pv = P[(size_t)s * 64 + d];   // gathered dword
        float pf = __uint_as_float(pv << 16);
        float psv = __uint_as_float(pv & 0xffff0000u);
        float xF = fmaf(ea, wf, qf + pf);
        float xS = fmaf(ea, ws, qs + psv);
        float sig = __builtin_amdgcn_rcpf(1.f + __expf(-xF));
        float t = __expf(-fabsf(xS));
        float sp = fmaxf(xS, 0.f) + __logf(1.f + t);
        agg = fmaf(sig, sp, agg);
    }

    float inv = 1.f / (float)max(re - rb, 1);
    size_t idx = (size_t)n * 64 + d;
    hout[idx] = fmaxf(h[idx] + agg * inv, 0.f);
}

// ---------------------------------------------------------------------------
// Graph segment starts: bm sorted; gstart[b] = first node of graph b.
// ---------------------------------------------------------------------------
__global__ __launch_bounds__(256) void gstart_kernel(
    const int* __restrict__ bm, int* __restrict__ gstart, int N)
{
    int i = blockIdx.x * blockDim.x + threadIdx.x;
    if (i >= N) return;
    int b = bm[i];
    int prev = (i == 0) ? -1 : bm[i - 1];
    for (int g = prev + 1; g <= b; ++g) gstart[g] = i;
    if (i == N - 1)
        for (int g = b + 1; g <= GB; ++g) gstart[g] = N;
}

// ---------------------------------------------------------------------------
// Segmented mean pool: one block per graph, no atomics.
// ---------------------------------------------------------------------------
__global__ __launch_bounds__(256) void pool_seg_kernel(
    const float* __restrict__ h, const int* __restrict__ gstart,
    float* __restrict__ g)
{
    int b = blockIdx.x;
    int s = gstart[b], e = gstart[b + 1];
    int d = threadIdx.x & 63;
    int w = threadIdx.x >> 6;
    float acc = 0.f;
    for (int n = s + w; n < e; n += 4)
        acc += h[(size_t)n * 64 + d];
    __shared__ float lds[256];
    lds[threadIdx.x] = acc;
    __syncthreads();
    if (w == 0) {
        acc = lds[d] + lds[64 + d] + lds[128 + d] + lds[192 + d];
        g[b * 64 + d] = acc / fmaxf((float)(e - s), 1.f);
    }
}

// ---------------------------------------------------------------------------
// Fused post-MLP (3 relu layers) + final dot + bias. One wave per graph.
// ---------------------------------------------------------------------------
__global__ __launch_bounds__(256) void postmlp_kernel(
    const float* __restrict__ g,
    const float* __restrict__ W0, const float* __restrict__ b0,
    const float* __restrict__ W1, const float* __restrict__ b1,
    const float* __restrict__ W2, const float* __restrict__ b2,
    const float* __restrict__ Wfin, const float* __restrict__ bfin,
    float* __restrict__ out)
{
    int b = blockIdx.x * 4 + (threadIdx.x >> 6);   // 32 blocks x 4 waves = 128
    int d = threadIdx.x & 63;
    float h = g[(size_t)b * 64 + d];

    float acc = b0[d];
#pragma unroll
    for (int k = 0; k < 64; ++k)
        acc = fmaf(__shfl(h, k, 64), W0[k * 64 + d], acc);
    h = fmaxf(acc, 0.f);

    acc = b1[d];
#pragma unroll
    for (int k = 0; k < 64; ++k)
        acc = fmaf(__shfl(h, k, 64), W1[k * 64 + d], acc);
    h = fmaxf(acc, 0.f);

    acc = b2[d];
#pragma unroll
    for (int k = 0; k < 64; ++k)
        acc = fmaf(__shfl(h, k, 64), W2[k * 64 + d], acc);
    h = fmaxf(acc, 0.f);

    float v = h * Wfin[d];
#pragma unroll
    for (int off = 32; off >= 1; off >>= 1)
        v += __shfl_xor(v, off, 64);
    if (d == 0) out[b] = v + bfin[0];
}

extern "C" void kernel_launch(void* const* d_in, const int* in_sizes, int n_in,
                              void* d_out, int out_size, void* d_ws, size_t ws_size,
                              hipStream_t stream)
{
    const float* X      = (const float*)d_in[0];
    const int*   eidx   = (const int*)d_in[1];
    const float* ea     = (const float*)d_in[3];
    const int*   bm     = (const int*)d_in[4];
    const float* pre_W0 = (const float*)d_in[5];
    const float* pre_b0 = (const float*)d_in[6];
    const float* pre_W1 = (const float*)d_in[7];
    const float* pre_b1 = (const float*)d_in[8];
    const float* pre_W2 = (const float*)d_in[9];
    const float* pre_b2 = (const float*)d_in[10];
    const float* cg_Wf  = (const float*)d_in[11];
    const float* cg_bf  = (const float*)d_in[12];
    const float* cg_Ws  = (const float*)d_in[13];
    const float* cg_bs  = (const float*)d_in[14];
    const float* post_W0 = (const float*)d_in[15];
    const float* post_b0 = (const float*)d_in[16];
    const float* post_W1 = (const float*)d_in[17];
    const float* post_b1 = (const float*)d_in[18];
    const float* post_W2 = (const float*)d_in[19];
    const float* post_b2 = (const float*)d_in[20];
    const float* post_Wf = (const float*)d_in[21];
    const float* post_bf = (const float*)d_in[22];

    const int* src = eidx;
    const int* dst = eidx + GE;

    // ---- workspace carve-up ----
    const size_t N64 = (size_t)GN * 64;
    float* hA    = (float*)d_ws;            // N*64
    float* hB    = hA + N64;                // N*64
    unsigned int* P = (unsigned int*)(hB + N64);  // N*64 packed bf16x2
    int* deg_i   = (int*)(P + N64);         // N
    int* iscan   = deg_i + GN;              // N
    int* bsum    = iscan + GN;              // 128
    int* boff    = bsum + 128;              // 128
    int* rowptr  = boff + 128;              // N+2 (padded so e_se is 8B-aligned)
    int* cursor  = rowptr + GN + 2;         // N
    int2* e_se   = (int2*)(cursor + GN);    // E int2 (8B-aligned)
    int* gstart  = (int*)(e_se + GE);       // B+1
    float* g0    = (float*)(gstart + GB + 1); // B*64

    const int TPB = 256;
    int gridE  = (GE + TPB - 1) / TPB;
    int gridN  = (GN + TPB - 1) / TPB;         // 391 (lane=node grid)
    int gridND = ((GN * 64) + TPB - 1) / TPB;  // 25000 (edge grid)
    int scanBlocks = (GN + 1023) / 1024;       // 98

    // per-layer weight pointers
    const float* Wf0 = cg_Wf;
    const float* Ws0 = cg_Ws;
    const float* Wf1 = cg_Wf + (size_t)1 * GZ * GD;
    const float* Ws1 = cg_Ws + (size_t)1 * GZ * GD;
    const float* Wf2 = cg_Wf + (size_t)2 * GZ * GD;
    const float* Ws2 = cg_Ws + (size_t)2 * GZ * GD;

    // fused pre-MLP (LDS-staged weights) + P0
    premlp_kernel<<<gridN, TPB, 0, stream>>>(
        X, pre_W0, pre_b0, pre_W1, pre_b1, pre_W2, pre_b2,
        Wf0 + 64 * 64, Ws0 + 64 * 64, hA, P, GN);

    // degree + CSR build
    hipMemsetAsync(deg_i, 0, GN * sizeof(int), stream);
    deg_kernel<<<gridE, TPB, 0, stream>>>(dst, deg_i, GE);
    scanA_kernel<<<scanBlocks, 1024, 0, stream>>>(deg_i, iscan, bsum, GN);
    scanB_kernel<<<1, 128, 0, stream>>>(bsum, boff, scanBlocks);
    scanC_kernel<<<gridN, TPB, 0, stream>>>(iscan, boff, deg_i, rowptr, cursor, GN);
    escatter_kernel<<<gridE, TPB, 0, stream>>>(src, dst, ea, cursor, e_se, GE);

    // graph segment starts (bm sorted)
    gstart_kernel<<<gridN, TPB, 0, stream>>>(bm, gstart, GN);

    // CGConv layers: plain edge + standalone pj for next layer
    edge_kernel<<<gridND, TPB, 0, stream>>>(
        hA, rowptr, e_se, P, Wf0, cg_bf, Ws0, cg_bs, hB);
    pj_kernel<<<gridN, TPB, 0, stream>>>(hB, Wf1, Ws1, P, GN);
    edge_kernel<<<gridND, TPB, 0, stream>>>(
        hB, rowptr, e_se, P, Wf1, cg_bf + GD, Ws1, cg_bs + GD, hA);
    pj_kernel<<<gridN, TPB, 0, stream>>>(hA, Wf2, Ws2, P, GN);
    edge_kernel<<<gridND, TPB, 0, stream>>>(
        hA, rowptr, e_se, P, Wf2, cg_bf + 2 * GD, Ws2, cg_bs + 2 * GD, hB);

    // segmented mean pool (no atomics)
    pool_seg_kernel<<<GB, TPB, 0, stream>>>(hB, gstart, g0);

    // fused post-MLP + final projection
    postmlp_kernel<<<GB / 4, TPB, 0, stream>>>(
        g0, post_W0, post_b0, post_W1, post_b1, post_W2, post_b2,
        post_Wf, post_bf, (float*)d_out);
}

// Round 2
// 983.716 us; speedup vs baseline: 1.2085x; 1.0585x over previous
//
#include <hip/hip_runtime.h>
#include <hip/hip_bf16.h>
#include <math.h>

// Problem constants (fixed by the reference)
#define GN 100000   // nodes
#define GE 1200000  // edges
#define GB 128      // graphs
#define GF 92       // raw features
#define GD 64       // hidden dim
#define GL 3        // CGConv layers
#define GZ 129      // 2*D+1

// round-to-nearest-even fp32 -> bf16 (returned in low 16 bits)
__device__ __forceinline__ unsigned int f2bf_rne(float x)
{
    unsigned int u = __float_as_uint(x);
    u += 0x7fffu + ((u >> 16) & 1u);
    return u >> 16;
}

// ---------------------------------------------------------------------------
// Fused pre-MLP (3 layers) + P0 + Q0, lane = node.
// R11: LDS-staged weights, rolled c-loops, acc[64] register blocking.
// R12: also emits Q0 = dst-half gate projection (bias folded), fp32 float2
// pairs, so edge_kernel no longer re-reads 32KB of weights per wave.
// Q accumulation order matches the old edge-kernel inline projection
// (k = c*4+i ascending) -> bitwise-identical q values.
// ---------------------------------------------------------------------------
__global__ __launch_bounds__(256, 2) void premlp_kernel(
    const float* __restrict__ X,
    const float* __restrict__ W0, const float* __restrict__ b0,
    const float* __restrict__ W1, const float* __restrict__ b1,
    const float* __restrict__ W2, const float* __restrict__ b2,
    const float* __restrict__ WfD, const float* __restrict__ WsD,   // rows 0..63
    const float* __restrict__ WfS, const float* __restrict__ WsS,   // rows 64..127
    const float* __restrict__ bf, const float* __restrict__ bs,
    float* __restrict__ hout, unsigned int* __restrict__ Pout,
    float* __restrict__ Qout, int N)
{
    __shared__ __align__(16) float Wl[8192];   // 32 KiB, reused per phase
    const int tid = threadIdx.x;
    const int n = blockIdx.x * 256 + tid;
    const int nn = (n < N) ? n : (N - 1);   // clamp so inactive lanes read safely
    const bool act = (n < N);

    float acc[64], accS[64];

    // ---------------- stage W0 (92x64 = 1472 float4) ----------------
    {
        const float4* __restrict__ s4 = (const float4*)W0;
        float4* __restrict__ d4 = (float4*)Wl;
        for (int i = tid; i < 1472; i += 256) d4[i] = s4[i];
    }
    __syncthreads();

    // ---------------- layer 0: K=92 ----------------
#pragma unroll
    for (int j = 0; j < 64; ++j) acc[j] = b0[j];
    {
        const float4* __restrict__ row4 = (const float4*)(X + (size_t)nn * GF);
#pragma unroll 2
        for (int c = 0; c < 23; ++c) {
            float4 v = row4[c];
            const float* __restrict__ w = Wl + c * 256;
#pragma unroll
            for (int j = 0; j < 64; ++j) {
                acc[j] = fmaf(v.x, w[j], acc[j]);
                acc[j] = fmaf(v.y, w[64 + j], acc[j]);
                acc[j] = fmaf(v.z, w[128 + j], acc[j]);
                acc[j] = fmaf(v.w, w[192 + j], acc[j]);
            }
        }
    }
    if (act) {
        float4* __restrict__ op = (float4*)(hout + (size_t)n * 64);
#pragma unroll
        for (int q = 0; q < 16; ++q)
            op[q] = make_float4(fmaxf(acc[q * 4], 0.f), fmaxf(acc[q * 4 + 1], 0.f),
                                fmaxf(acc[q * 4 + 2], 0.f), fmaxf(acc[q * 4 + 3], 0.f));
    }

    // ---------------- stage W1 ----------------
    __syncthreads();
    {
        const float4* __restrict__ s4 = (const float4*)W1;
        float4* __restrict__ d4 = (float4*)Wl;
        for (int i = tid; i < 1024; i += 256) d4[i] = s4[i];
    }
    __syncthreads();

    // ---------------- layer 1 ----------------
#pragma unroll
    for (int j = 0; j < 64; ++j) acc[j] = b1[j];
    {
        const float4* __restrict__ row4 = (const float4*)(hout + (size_t)nn * 64);
#pragma unroll 2
        for (int c = 0; c < 16; ++c) {
            float4 v = row4[c];
            const float* __restrict__ w = Wl + c * 256;
#pragma unroll
            for (int j = 0; j < 64; ++j) {
                acc[j] = fmaf(v.x, w[j], acc[j]);
                acc[j] = fmaf(v.y, w[64 + j], acc[j]);
                acc[j] = fmaf(v.z, w[128 + j], acc[j]);
                acc[j] = fmaf(v.w, w[192 + j], acc[j]);
            }
        }
    }
    if (act) {
        float4* __restrict__ op = (float4*)(hout + (size_t)n * 64);
#pragma unroll
        for (int q = 0; q < 16; ++q)
            op[q] = make_float4(fmaxf(acc[q * 4], 0.f), fmaxf(acc[q * 4 + 1], 0.f),
                                fmaxf(acc[q * 4 + 2], 0.f), fmaxf(acc[q * 4 + 3], 0.f));
    }

    // ---------------- stage W2 ----------------
    __syncthreads();
    {
        const float4* __restrict__ s4 = (const float4*)W2;
        float4* __restrict__ d4 = (float4*)Wl;
        for (int i = tid; i < 1024; i += 256) d4[i] = s4[i];
    }
    __syncthreads();

    // ---------------- layer 2 ----------------
#pragma unroll
    for (int j = 0; j < 64; ++j) acc[j] = b2[j];
    {
        const float4* __restrict__ row4 = (const float4*)(hout + (size_t)nn * 64);
#pragma unroll 2
        for (int c = 0; c < 16; ++c) {
            float4 v = row4[c];
            const float* __restrict__ w = Wl + c * 256;
#pragma unroll
            for (int j = 0; j < 64; ++j) {
                acc[j] = fmaf(v.x, w[j], acc[j]);
                acc[j] = fmaf(v.y, w[64 + j], acc[j]);
                acc[j] = fmaf(v.z, w[128 + j], acc[j]);
                acc[j] = fmaf(v.w, w[192 + j], acc[j]);
            }
        }
    }
    if (act) {
        float4* __restrict__ op = (float4*)(hout + (size_t)n * 64);
#pragma unroll
        for (int q = 0; q < 16; ++q)
            op[q] = make_float4(fmaxf(acc[q * 4], 0.f), fmaxf(acc[q * 4 + 1], 0.f),
                                fmaxf(acc[q * 4 + 2], 0.f), fmaxf(acc[q * 4 + 3], 0.f));
    }

    // ---------------- P0: src-half gate projection, packed bf16 ----------------
    __syncthreads();
    {
        const float4* __restrict__ s4 = (const float4*)WfS;
        const float4* __restrict__ t4 = (const float4*)WsS;
        float4* __restrict__ d4 = (float4*)Wl;
        for (int i = tid; i < 1024; i += 256) {
            d4[i] = s4[i];
            d4[1024 + i] = t4[i];
        }
    }
    __syncthreads();

#pragma unroll
    for (int j = 0; j < 64; ++j) { acc[j] = 0.f; accS[j] = 0.f; }
    {
        const float4* __restrict__ row4 = (const float4*)(hout + (size_t)nn * 64);
#pragma unroll 2
        for (int c = 0; c < 16; ++c) {
            float4 v = row4[c];
            const float* __restrict__ wf = Wl + c * 256;
            const float* __restrict__ ws = Wl + 4096 + c * 256;
#pragma unroll
            for (int j = 0; j < 64; ++j) {
                acc[j] = fmaf(v.x, wf[j], acc[j]);
                acc[j] = fmaf(v.y, wf[64 + j], acc[j]);
                acc[j] = fmaf(v.z, wf[128 + j], acc[j]);
                acc[j] = fmaf(v.w, wf[192 + j], acc[j]);
                accS[j] = fmaf(v.x, ws[j], accS[j]);
                accS[j] = fmaf(v.y, ws[64 + j], accS[j]);
                accS[j] = fmaf(v.z, ws[128 + j], accS[j]);
                accS[j] = fmaf(v.w, ws[192 + j], accS[j]);
            }
        }
    }
    if (act) {
        uint4* __restrict__ pp = (uint4*)(Pout + (size_t)n * 64);
#pragma unroll
        for (int q = 0; q < 16; ++q) {
            uint4 pk;
            pk.x = f2bf_rne(acc[q * 4])     | (f2bf_rne(accS[q * 4]) << 16);
            pk.y = f2bf_rne(acc[q * 4 + 1]) | (f2bf_rne(accS[q * 4 + 1]) << 16);
            pk.z = f2bf_rne(acc[q * 4 + 2]) | (f2bf_rne(accS[q * 4 + 2]) << 16);
            pk.w = f2bf_rne(acc[q * 4 + 3]) | (f2bf_rne(accS[q * 4 + 3]) << 16);
            pp[q] = pk;
        }
    }

    // ---------------- Q0: dst-half gate projection + bias, fp32 pairs ----------------
    __syncthreads();
    {
        const float4* __restrict__ s4 = (const float4*)WfD;
        const float4* __restrict__ t4 = (const float4*)WsD;
        float4* __restrict__ d4 = (float4*)Wl;
        for (int i = tid; i < 1024; i += 256) {
            d4[i] = s4[i];
            d4[1024 + i] = t4[i];
        }
    }
    __syncthreads();

#pragma unroll
    for (int j = 0; j < 64; ++j) { acc[j] = bf[j]; accS[j] = bs[j]; }
    {
        const float4* __restrict__ row4 = (const float4*)(hout + (size_t)nn * 64);
#pragma unroll 2
        for (int c = 0; c < 16; ++c) {
            float4 v = row4[c];
            const float* __restrict__ wf = Wl + c * 256;
            const float* __restrict__ ws = Wl + 4096 + c * 256;
#pragma unroll
            for (int j = 0; j < 64; ++j) {
                acc[j] = fmaf(v.x, wf[j], acc[j]);
                acc[j] = fmaf(v.y, wf[64 + j], acc[j]);
                acc[j] = fmaf(v.z, wf[128 + j], acc[j]);
                acc[j] = fmaf(v.w, wf[192 + j], acc[j]);
                accS[j] = fmaf(v.x, ws[j], accS[j]);
                accS[j] = fmaf(v.y, ws[64 + j], accS[j]);
                accS[j] = fmaf(v.z, ws[128 + j], accS[j]);
                accS[j] = fmaf(v.w, ws[192 + j], accS[j]);
            }
        }
    }
    if (act) {
        float4* __restrict__ qp = (float4*)(Qout + (size_t)n * 128);
#pragma unroll
        for (int q = 0; q < 32; ++q)
            qp[q] = make_float4(acc[q * 2], accS[q * 2], acc[q * 2 + 1], accS[q * 2 + 1]);
    }
}

// ---------------------------------------------------------------------------
// Gate projections for one CGConv layer: P (src half, packed bf16) and
// Q (dst half + bias, fp32 (qf,qs) pairs). lane = node, LDS-staged weights.
// ---------------------------------------------------------------------------
__global__ __launch_bounds__(256, 2) void pjq_kernel(
    const float* __restrict__ h,
    const float* __restrict__ Wf, const float* __restrict__ Ws,
    const float* __restrict__ bfv, const float* __restrict__ bsv,
    unsigned int* __restrict__ P, float* __restrict__ Q, int N)
{
    __shared__ __align__(16) float Wl[8192];
    const int tid = threadIdx.x;
    const int n = blockIdx.x * 256 + tid;
    const int nn = (n < N) ? n : (N - 1);
    const bool act = (n < N);

    float aF[64], aS[64];

    // ---------------- phase 1: P (rows 64..127) ----------------
    {
        const float4* __restrict__ s4 = (const float4*)(Wf + 64 * 64);
        const float4* __restrict__ t4 = (const float4*)(Ws + 64 * 64);
        float4* __restrict__ d4 = (float4*)Wl;
        for (int i = tid; i < 1024; i += 256) {
            d4[i] = s4[i];
            d4[1024 + i] = t4[i];
        }
    }
    __syncthreads();

#pragma unroll
    for (int j = 0; j < 64; ++j) { aF[j] = 0.f; aS[j] = 0.f; }
    {
        const float4* __restrict__ row4 = (const float4*)(h + (size_t)nn * 64);
#pragma unroll 2
        for (int c = 0; c < 16; ++c) {
            float4 v = row4[c];
            const float* __restrict__ wf = Wl + c * 256;
            const float* __restrict__ ws = Wl + 4096 + c * 256;
#pragma unroll
            for (int j = 0; j < 64; ++j) {
                aF[j] = fmaf(v.x, wf[j], aF[j]);
                aF[j] = fmaf(v.y, wf[64 + j], aF[j]);
                aF[j] = fmaf(v.z, wf[128 + j], aF[j]);
                aF[j] = fmaf(v.w, wf[192 + j], aF[j]);
                aS[j] = fmaf(v.x, ws[j], aS[j]);
                aS[j] = fmaf(v.y, ws[64 + j], aS[j]);
                aS[j] = fmaf(v.z, ws[128 + j], aS[j]);
                aS[j] = fmaf(v.w, ws[192 + j], aS[j]);
            }
        }
    }
    if (act) {
        uint4* __restrict__ pp = (uint4*)(P + (size_t)n * 64);
#pragma unroll
        for (int q = 0; q < 16; ++q) {
            uint4 pk;
            pk.x = f2bf_rne(aF[q * 4])     | (f2bf_rne(aS[q * 4]) << 16);
            pk.y = f2bf_rne(aF[q * 4 + 1]) | (f2bf_rne(aS[q * 4 + 1]) << 16);
            pk.z = f2bf_rne(aF[q * 4 + 2]) | (f2bf_rne(aS[q * 4 + 2]) << 16);
            pk.w = f2bf_rne(aF[q * 4 + 3]) | (f2bf_rne(aS[q * 4 + 3]) << 16);
            pp[q] = pk;
        }
    }

    // ---------------- phase 2: Q (rows 0..63 + bias) ----------------
    __syncthreads();
    {
        const float4* __restrict__ s4 = (const float4*)Wf;
        const float4* __restrict__ t4 = (const float4*)Ws;
        float4* __restrict__ d4 = (float4*)Wl;
        for (int i = tid; i < 1024; i += 256) {
            d4[i] = s4[i];
            d4[1024 + i] = t4[i];
        }
    }
    __syncthreads();

#pragma unroll
    for (int j = 0; j < 64; ++j) { aF[j] = bfv[j]; aS[j] = bsv[j]; }
    {
        const float4* __restrict__ row4 = (const float4*)(h + (size_t)nn * 64);
#pragma unroll 2
        for (int c = 0; c < 16; ++c) {
            float4 v = row4[c];
            const float* __restrict__ wf = Wl + c * 256;
            const float* __restrict__ ws = Wl + 4096 + c * 256;
#pragma unroll
            for (int j = 0; j < 64; ++j) {
                aF[j] = fmaf(v.x, wf[j], aF[j]);
                aF[j] = fmaf(v.y, wf[64 + j], aF[j]);
                aF[j] = fmaf(v.z, wf[128 + j], aF[j]);
                aF[j] = fmaf(v.w, wf[192 + j], aF[j]);
                aS[j] = fmaf(v.x, ws[j], aS[j]);
                aS[j] = fmaf(v.y, ws[64 + j], aS[j]);
                aS[j] = fmaf(v.z, ws[128 + j], aS[j]);
                aS[j] = fmaf(v.w, ws[192 + j], aS[j]);
            }
        }
    }
    if (act) {
        float4* __restrict__ qp = (float4*)(Q + (size_t)n * 128);
#pragma unroll
        for (int q = 0; q < 32; ++q)
            qp[q] = make_float4(aF[q * 2], aS[q * 2], aF[q * 2 + 1], aS[q * 2 + 1]);
    }
}

// ---------------------------------------------------------------------------
// In-degree histogram (int)
// ---------------------------------------------------------------------------
__global__ __launch_bounds__(256) void deg_kernel(
    const int* __restrict__ dst, int* __restrict__ deg, int E)
{
    int e = blockIdx.x * blockDim.x + threadIdx.x;
    if (e < E) atomicAdd(&deg[dst[e]], 1);
}

// ---------------------------------------------------------------------------
// Three-phase exclusive scan over deg -> rowptr, cursor
// ---------------------------------------------------------------------------
__global__ __launch_bounds__(1024) void scanA_kernel(
    const int* __restrict__ deg, int* __restrict__ iscan,
    int* __restrict__ bsum, int N)
{
    __shared__ int lds[1024];
    int tid = threadIdx.x;
    int gid = blockIdx.x * 1024 + tid;
    int v = (gid < N) ? deg[gid] : 0;
    lds[tid] = v; __syncthreads();
    for (int off = 1; off < 1024; off <<= 1) {
        int t = (tid >= off) ? lds[tid - off] : 0;
        __syncthreads();
        lds[tid] += t;
        __syncthreads();
    }
    if (gid < N) iscan[gid] = lds[tid];
    if (tid == 1023) bsum[blockIdx.x] = lds[1023];
}

__global__ __launch_bounds__(128) void scanB_kernel(
    const int* __restrict__ bsum, int* __restrict__ boff, int nb)
{
    __shared__ int lds[128];
    int t = threadIdx.x;
    int v = (t < nb) ? bsum[t] : 0;
    lds[t] = v; __syncthreads();
    for (int off = 1; off < 128; off <<= 1) {
        int u = (t >= off) ? lds[t - off] : 0;
        __syncthreads();
        lds[t] += u;
        __syncthreads();
    }
    if (t < nb) boff[t] = lds[t] - v;  // exclusive
}

__global__ __launch_bounds__(256) void scanC_kernel(
    const int* __restrict__ iscan, const int* __restrict__ boff,
    const int* __restrict__ deg,
    int* __restrict__ rowptr, int* __restrict__ cursor, int N)
{
    int i = blockIdx.x * blockDim.x + threadIdx.x;
    if (i >= N) return;
    int incl = iscan[i] + boff[i >> 10];
    rowptr[i + 1] = incl;
    cursor[i] = incl - deg[i];
    if (i == 0) rowptr[0] = 0;
}

// ---------------------------------------------------------------------------
// Edge scatter into CSR order, packed (src, ea) int2
// ---------------------------------------------------------------------------
__global__ __launch_bounds__(256) void escatter_kernel(
    const int* __restrict__ src, const int* __restrict__ dst,
    const float* __restrict__ ea, int* __restrict__ cursor,
    int2* __restrict__ e_se, int E)
{
    int e = blockIdx.x * blockDim.x + threadIdx.x;
    if (e >= E) return;
    int pos = atomicAdd(&cursor[dst[e]], 1);
    e_se[pos] = make_int2(src[e], __float_as_int(ea[e]));
}

// ---------------------------------------------------------------------------
// CGConv edge pass. One wave per node, lane = dim.
// R12: dst projection precomputed (Q float2 pairs) -> prologue is one 8B
// load per lane instead of 128 weight loads + 128 FMAs (was ~12.9 MB of L2
// traffic per CU, ~half the kernel).
// ---------------------------------------------------------------------------
__global__ __launch_bounds__(256) void edge_kernel(
    const float* __restrict__ h, const int* __restrict__ rowptr,
    const int2* __restrict__ e_se,
    const unsigned int* __restrict__ P,
    const float* __restrict__ Q,
    const float* __restrict__ Wf, const float* __restrict__ Ws,
    float* __restrict__ hout)
{
    int n = blockIdx.x * 4 + (threadIdx.x >> 6);   // grid exactly covers GN
    int d = threadIdx.x & 63;

    const float2 qv = ((const float2*)Q)[(size_t)n * 64 + d];
    float qf = qv.x, qs = qv.y;
    float wf = Wf[128 * 64 + d];
    float ws = Ws[128 * 64 + d];

    size_t idx = (size_t)n * 64 + d;
    float hres = h[idx];

    int rb = rowptr[n], re = rowptr[n + 1];
    float agg = 0.f;
#pragma unroll 8
    for (int p = rb; p < re; ++p) {
        int2 se = e_se[p];         // wave-uniform 8B load
        int s = se.x;
        float ea = __int_as_float(se.y);
        unsigned int pv = P[(size_t)s * 64 + d];   // gathered dword (256B/wave)
        float pf = __uint_as_float(pv << 16);
        float psv = __uint_as_float(pv & 0xffff0000u);
        float xF = fmaf(ea, wf, qf + pf);
        float xS = fmaf(ea, ws, qs + psv);
        float sig = __builtin_amdgcn_rcpf(1.f + __expf(-xF));
        float t = __expf(-fabsf(xS));
        float sp = fmaxf(xS, 0.f) + __logf(1.f + t);
        agg = fmaf(sig, sp, agg);
    }

    float inv = 1.f / (float)max(re - rb, 1);
    hout[idx] = fmaxf(hres + agg * inv, 0.f);
}

// ---------------------------------------------------------------------------
// Graph segment starts: bm sorted; gstart[b] = first node of graph b.
// ---------------------------------------------------------------------------
__global__ __launch_bounds__(256) void gstart_kernel(
    const int* __restrict__ bm, int* __restrict__ gstart, int N)
{
    int i = blockIdx.x * blockDim.x + threadIdx.x;
    if (i >= N) return;
    int b = bm[i];
    int prev = (i == 0) ? -1 : bm[i - 1];
    for (int g = prev + 1; g <= b; ++g) gstart[g] = i;
    if (i == N - 1)
        for (int g = b + 1; g <= GB; ++g) gstart[g] = N;
}

// ---------------------------------------------------------------------------
// Segmented mean pool: one block per graph, no atomics.
// ---------------------------------------------------------------------------
__global__ __launch_bounds__(256) void pool_seg_kernel(
    const float* __restrict__ h, const int* __restrict__ gstart,
    float* __restrict__ g)
{
    int b = blockIdx.x;
    int s = gstart[b], e = gstart[b + 1];
    int d = threadIdx.x & 63;
    int w = threadIdx.x >> 6;
    float acc = 0.f;
    for (int n = s + w; n < e; n += 4)
        acc += h[(size_t)n * 64 + d];
    __shared__ float lds[256];
    lds[threadIdx.x] = acc;
    __syncthreads();
    if (w == 0) {
        acc = lds[d] + lds[64 + d] + lds[128 + d] + lds[192 + d];
        g[b * 64 + d] = acc / fmaxf((float)(e - s), 1.f);
    }
}

// ---------------------------------------------------------------------------
// Fused post-MLP (3 relu layers) + final dot + bias. One wave per graph.
// ---------------------------------------------------------------------------
__global__ __launch_bounds__(256) void postmlp_kernel(
    const float* __restrict__ g,
    const float* __restrict__ W0, const float* __restrict__ b0,
    const float* __restrict__ W1, const float* __restrict__ b1,
    const float* __restrict__ W2, const float* __restrict__ b2,
    const float* __restrict__ Wfin, const float* __restrict__ bfin,
    float* __restrict__ out)
{
    int b = blockIdx.x * 4 + (threadIdx.x >> 6);   // 32 blocks x 4 waves = 128
    int d = threadIdx.x & 63;
    float h = g[(size_t)b * 64 + d];

    float acc = b0[d];
#pragma unroll
    for (int k = 0; k < 64; ++k)
        acc = fmaf(__shfl(h, k, 64), W0[k * 64 + d], acc);
    h = fmaxf(acc, 0.f);

    acc = b1[d];
#pragma unroll
    for (int k = 0; k < 64; ++k)
        acc = fmaf(__shfl(h, k, 64), W1[k * 64 + d], acc);
    h = fmaxf(acc, 0.f);

    acc = b2[d];
#pragma unroll
    for (int k = 0; k < 64; ++k)
        acc = fmaf(__shfl(h, k, 64), W2[k * 64 + d], acc);
    h = fmaxf(acc, 0.f);

    float v = h * Wfin[d];
#pragma unroll
    for (int off = 32; off >= 1; off >>= 1)
        v += __shfl_xor(v, off, 64);
    if (d == 0) out[b] = v + bfin[0];
}

extern "C" void kernel_launch(void* const* d_in, const int* in_sizes, int n_in,
                              void* d_out, int out_size, void* d_ws, size_t ws_size,
                              hipStream_t stream)
{
    const float* X      = (const float*)d_in[0];
    const int*   eidx   = (const int*)d_in[1];
    const float* ea     = (const float*)d_in[3];
    const int*   bm     = (const int*)d_in[4];
    const float* pre_W0 = (const float*)d_in[5];
    const float* pre_b0 = (const float*)d_in[6];
    const float* pre_W1 = (const float*)d_in[7];
    const float* pre_b1 = (const float*)d_in[8];
    const float* pre_W2 = (const float*)d_in[9];
    const float* pre_b2 = (const float*)d_in[10];
    const float* cg_Wf  = (const float*)d_in[11];
    const float* cg_bf  = (const float*)d_in[12];
    const float* cg_Ws  = (const float*)d_in[13];
    const float* cg_bs  = (const float*)d_in[14];
    const float* post_W0 = (const float*)d_in[15];
    const float* post_b0 = (const float*)d_in[16];
    const float* post_W1 = (const float*)d_in[17];
    const float* post_b1 = (const float*)d_in[18];
    const float* post_W2 = (const float*)d_in[19];
    const float* post_b2 = (const float*)d_in[20];
    const float* post_Wf = (const float*)d_in[21];
    const float* post_bf = (const float*)d_in[22];

    const int* src = eidx;
    const int* dst = eidx + GE;

    // ---- workspace carve-up ----
    const size_t N64 = (size_t)GN * 64;
    float* hA    = (float*)d_ws;            // N*64
    float* hB    = hA + N64;                // N*64
    unsigned int* P = (unsigned int*)(hB + N64);  // N*64 packed bf16x2
    int* deg_i   = (int*)(P + N64);         // N
    int* iscan   = deg_i + GN;              // N
    int* bsum    = iscan + GN;              // 128
    int* boff    = bsum + 128;              // 128
    int* rowptr  = boff + 128;              // N+2 (padded so e_se is 8B-aligned)
    int* cursor  = rowptr + GN + 2;         // N
    int2* e_se   = (int2*)(cursor + GN);    // E int2 (8B-aligned)
    int* gstart  = (int*)(e_se + GE);       // B+1
    float* g0    = (float*)(gstart + GB + 1); // B*64 (8192 floats, keeps 8B align)
    float* Q     = g0 + (size_t)GB * 64;    // N*128 fp32 (qf,qs) pairs

    const int TPB = 256;
    int gridE  = (GE + TPB - 1) / TPB;
    int gridN  = (GN + TPB - 1) / TPB;         // 391 (lane=node grid)
    int gridND = ((GN * 64) + TPB - 1) / TPB;  // 25000 (edge grid)
    int scanBlocks = (GN + 1023) / 1024;       // 98

    // per-layer weight pointers
    const float* Wf0 = cg_Wf;
    const float* Ws0 = cg_Ws;
    const float* Wf1 = cg_Wf + (size_t)1 * GZ * GD;
    const float* Ws1 = cg_Ws + (size_t)1 * GZ * GD;
    const float* Wf2 = cg_Wf + (size_t)2 * GZ * GD;
    const float* Ws2 = cg_Ws + (size_t)2 * GZ * GD;

    // fused pre-MLP (LDS-staged weights) + P0 + Q0
    premlp_kernel<<<gridN, TPB, 0, stream>>>(
        X, pre_W0, pre_b0, pre_W1, pre_b1, pre_W2, pre_b2,
        Wf0, Ws0, Wf0 + 64 * 64, Ws0 + 64 * 64, cg_bf, cg_bs,
        hA, P, Q, GN);

    // degree + CSR build
    hipMemsetAsync(deg_i, 0, GN * sizeof(int), stream);
    deg_kernel<<<gridE, TPB, 0, stream>>>(dst, deg_i, GE);
    scanA_kernel<<<scanBlocks, 1024, 0, stream>>>(deg_i, iscan, bsum, GN);
    scanB_kernel<<<1, 128, 0, stream>>>(bsum, boff, scanBlocks);
    scanC_kernel<<<gridN, TPB, 0, stream>>>(iscan, boff, deg_i, rowptr, cursor, GN);
    escatter_kernel<<<gridE, TPB, 0, stream>>>(src, dst, ea, cursor, e_se, GE);

    // graph segment starts (bm sorted)
    gstart_kernel<<<gridN, TPB, 0, stream>>>(bm, gstart, GN);

    // CGConv layers: lean edge pass + fused P/Q projection for next layer
    edge_kernel<<<gridND, TPB, 0, stream>>>(
        hA, rowptr, e_se, P, Q, Wf0, Ws0, hB);
    pjq_kernel<<<gridN, TPB, 0, stream>>>(
        hB, Wf1, Ws1, cg_bf + GD, cg_bs + GD, P, Q, GN);
    edge_kernel<<<gridND, TPB, 0, stream>>>(
        hB, rowptr, e_se, P, Q, Wf1, Ws1, hA);
    pjq_kernel<<<gridN, TPB, 0, stream>>>(
        hA, Wf2, Ws2, cg_bf + 2 * GD, cg_bs + 2 * GD, P, Q, GN);
    edge_kernel<<<gridND, TPB, 0, stream>>>(
        hA, rowptr, e_se, P, Q, Wf2, Ws2, hB);

    // segmented mean pool (no atomics)
    pool_seg_kernel<<<GB, TPB, 0, stream>>>(hB, gstart, g0);

    // fused post-MLP + final projection
    postmlp_kernel<<<GB / 4, TPB, 0, stream>>>(
        g0, post_W0, post_b0, post_W1, post_b1, post_W2, post_b2,
        post_Wf, post_bf, (float*)d_out);
}

// Round 3
// 894.682 us; speedup vs baseline: 1.3287x; 1.0995x over previous
//
#include <hip/hip_runtime.h>
#include <hip/hip_bf16.h>
#include <math.h>

// Problem constants (fixed by the reference)
#define GN 100000   // nodes
#define GE 1200000  // edges
#define GB 128      // graphs
#define GF 92       // raw features
#define GD 64       // hidden dim
#define GL 3        // CGConv layers
#define GZ 129      // 2*D+1

#define HS 65       // padded LDS h-tile stride (bank = (lane + k) & 31, 2-way alias = free)

// round-to-nearest-even fp32 -> bf16 (returned in low 16 bits)
__device__ __forceinline__ unsigned int f2bf_rne(float x)
{
    unsigned int u = __float_as_uint(x);
    u += 0x7fffu + ((u >> 16) & 1u);
    return u >> 16;
}

// ---------------------------------------------------------------------------
// Fused pre-MLP (3 layers) + P0 + Q0.
// R13: 4-way column split. Block = 64 nodes x 4 waves (wave = 16-col slice),
// grid 1563 -> 16 waves/CU (was 391 blocks, 1.2 waves/SIMD, VALUBusy 30%).
// Layers chain through a padded LDS h-tile; weights staged per phase in LDS.
// Accumulation order per output element identical to R12 (bitwise-same).
// ---------------------------------------------------------------------------
__global__ __launch_bounds__(256, 4) void premlp_kernel(
    const float* __restrict__ X,
    const float* __restrict__ W0, const float* __restrict__ b0,
    const float* __restrict__ W1, const float* __restrict__ b1,
    const float* __restrict__ W2, const float* __restrict__ b2,
    const float* __restrict__ WfD, const float* __restrict__ WsD,   // rows 0..63
    const float* __restrict__ WsS, const float* __restrict__ WfS,   // rows 64..127 (order fixed below)
    const float* __restrict__ bf, const float* __restrict__ bs,
    float* __restrict__ hout, unsigned int* __restrict__ Pout,
    float* __restrict__ Qout, int N)
{
    __shared__ __align__(16) float Wl[5888];    // 23 KB weight stage (W0 needs all of it)
    __shared__ float hl[64 * HS];               // 16.6 KB padded h tile
    const int tid = threadIdx.x;
    const int lane = tid & 63;                  // node within block
    const int col0 = (tid >> 6) * 16;           // this wave's column slice
    const int base = blockIdx.x * 64;
    const int n = base + lane;
    const int nn = (n < N) ? n : (N - 1);       // clamp so inactive lanes read safely
    const bool act = (n < N);

    float acc[16], acc2[16];

    // ---- stage W0 (92x64 = 1472 float4) ----
    {
        const float4* __restrict__ s4 = (const float4*)W0;
        float4* __restrict__ d4 = (float4*)Wl;
        for (int i = tid; i < 1472; i += 256) d4[i] = s4[i];
    }
    __syncthreads();

    // ---- layer 0: K=92 ----
#pragma unroll
    for (int j = 0; j < 16; ++j) acc[j] = b0[col0 + j];
    {
        const float4* __restrict__ row4 = (const float4*)(X + (size_t)nn * GF);
        for (int c = 0; c < 23; ++c) {
            float4 v = row4[c];
            const float* __restrict__ w = Wl + c * 256 + col0;
#pragma unroll
            for (int j = 0; j < 16; ++j) {
                acc[j] = fmaf(v.x, w[j], acc[j]);
                acc[j] = fmaf(v.y, w[64 + j], acc[j]);
                acc[j] = fmaf(v.z, w[128 + j], acc[j]);
                acc[j] = fmaf(v.w, w[192 + j], acc[j]);
            }
        }
    }
    __syncthreads();    // all Wl reads done
    // write h0 slice; stage W1 (disjoint LDS regions)
#pragma unroll
    for (int j = 0; j < 16; ++j) hl[lane * HS + col0 + j] = fmaxf(acc[j], 0.f);
    {
        const float4* __restrict__ s4 = (const float4*)W1;
        float4* __restrict__ d4 = (float4*)Wl;
        for (int i = tid; i < 1024; i += 256) d4[i] = s4[i];
    }
    __syncthreads();

    // ---- layer 1 ----
#pragma unroll
    for (int j = 0; j < 16; ++j) acc[j] = b1[col0 + j];
    for (int c = 0; c < 16; ++c) {
        float h0 = hl[lane * HS + 4 * c + 0];
        float h1 = hl[lane * HS + 4 * c + 1];
        float h2 = hl[lane * HS + 4 * c + 2];
        float h3 = hl[lane * HS + 4 * c + 3];
        const float* __restrict__ w = Wl + c * 256 + col0;
#pragma unroll
        for (int j = 0; j < 16; ++j) {
            acc[j] = fmaf(h0, w[j], acc[j]);
            acc[j] = fmaf(h1, w[64 + j], acc[j]);
            acc[j] = fmaf(h2, w[128 + j], acc[j]);
            acc[j] = fmaf(h3, w[192 + j], acc[j]);
        }
    }
    __syncthreads();    // hl + Wl reads done
#pragma unroll
    for (int j = 0; j < 16; ++j) hl[lane * HS + col0 + j] = fmaxf(acc[j], 0.f);
    {
        const float4* __restrict__ s4 = (const float4*)W2;
        float4* __restrict__ d4 = (float4*)Wl;
        for (int i = tid; i < 1024; i += 256) d4[i] = s4[i];
    }
    __syncthreads();

    // ---- layer 2 ----
#pragma unroll
    for (int j = 0; j < 16; ++j) acc[j] = b2[col0 + j];
    for (int c = 0; c < 16; ++c) {
        float h0 = hl[lane * HS + 4 * c + 0];
        float h1 = hl[lane * HS + 4 * c + 1];
        float h2 = hl[lane * HS + 4 * c + 2];
        float h3 = hl[lane * HS + 4 * c + 3];
        const float* __restrict__ w = Wl + c * 256 + col0;
#pragma unroll
        for (int j = 0; j < 16; ++j) {
            acc[j] = fmaf(h0, w[j], acc[j]);
            acc[j] = fmaf(h1, w[64 + j], acc[j]);
            acc[j] = fmaf(h2, w[128 + j], acc[j]);
            acc[j] = fmaf(h3, w[192 + j], acc[j]);
        }
    }
    __syncthreads();    // hl + Wl reads done
    // final h: write LDS tile + global slice; stage WfS
#pragma unroll
    for (int j = 0; j < 16; ++j) hl[lane * HS + col0 + j] = fmaxf(acc[j], 0.f);
    if (act) {
        float4* __restrict__ op = (float4*)(hout + (size_t)n * 64 + col0);
#pragma unroll
        for (int q = 0; q < 4; ++q)
            op[q] = make_float4(fmaxf(acc[q * 4], 0.f), fmaxf(acc[q * 4 + 1], 0.f),
                                fmaxf(acc[q * 4 + 2], 0.f), fmaxf(acc[q * 4 + 3], 0.f));
    }
    {
        const float4* __restrict__ s4 = (const float4*)WfS;
        float4* __restrict__ d4 = (float4*)Wl;
        for (int i = tid; i < 1024; i += 256) d4[i] = s4[i];
    }
    __syncthreads();

    // ---- P0-F ----
#pragma unroll
    for (int j = 0; j < 16; ++j) acc[j] = 0.f;
    for (int c = 0; c < 16; ++c) {
        float h0 = hl[lane * HS + 4 * c + 0];
        float h1 = hl[lane * HS + 4 * c + 1];
        float h2 = hl[lane * HS + 4 * c + 2];
        float h3 = hl[lane * HS + 4 * c + 3];
        const float* __restrict__ w = Wl + c * 256 + col0;
#pragma unroll
        for (int j = 0; j < 16; ++j) {
            acc[j] = fmaf(h0, w[j], acc[j]);
            acc[j] = fmaf(h1, w[64 + j], acc[j]);
            acc[j] = fmaf(h2, w[128 + j], acc[j]);
            acc[j] = fmaf(h3, w[192 + j], acc[j]);
        }
    }
    __syncthreads();
    {
        const float4* __restrict__ s4 = (const float4*)WsS;
        float4* __restrict__ d4 = (float4*)Wl;
        for (int i = tid; i < 1024; i += 256) d4[i] = s4[i];
    }
    __syncthreads();

    // ---- P0-S + store ----
#pragma unroll
    for (int j = 0; j < 16; ++j) acc2[j] = 0.f;
    for (int c = 0; c < 16; ++c) {
        float h0 = hl[lane * HS + 4 * c + 0];
        float h1 = hl[lane * HS + 4 * c + 1];
        float h2 = hl[lane * HS + 4 * c + 2];
        float h3 = hl[lane * HS + 4 * c + 3];
        const float* __restrict__ w = Wl + c * 256 + col0;
#pragma unroll
        for (int j = 0; j < 16; ++j) {
            acc2[j] = fmaf(h0, w[j], acc2[j]);
            acc2[j] = fmaf(h1, w[64 + j], acc2[j]);
            acc2[j] = fmaf(h2, w[128 + j], acc2[j]);
            acc2[j] = fmaf(h3, w[192 + j], acc2[j]);
        }
    }
    if (act) {
        uint4* __restrict__ pp = (uint4*)(Pout + (size_t)n * 64 + col0);
#pragma unroll
        for (int q = 0; q < 4; ++q) {
            uint4 pk;
            pk.x = f2bf_rne(acc[q * 4])     | (f2bf_rne(acc2[q * 4]) << 16);
            pk.y = f2bf_rne(acc[q * 4 + 1]) | (f2bf_rne(acc2[q * 4 + 1]) << 16);
            pk.z = f2bf_rne(acc[q * 4 + 2]) | (f2bf_rne(acc2[q * 4 + 2]) << 16);
            pk.w = f2bf_rne(acc[q * 4 + 3]) | (f2bf_rne(acc2[q * 4 + 3]) << 16);
            pp[q] = pk;
        }
    }
    __syncthreads();
    {
        const float4* __restrict__ s4 = (const float4*)WfD;
        float4* __restrict__ d4 = (float4*)Wl;
        for (int i = tid; i < 1024; i += 256) d4[i] = s4[i];
    }
    __syncthreads();

    // ---- Q0-F ----
#pragma unroll
    for (int j = 0; j < 16; ++j) acc[j] = bf[col0 + j];
    for (int c = 0; c < 16; ++c) {
        float h0 = hl[lane * HS + 4 * c + 0];
        float h1 = hl[lane * HS + 4 * c + 1];
        float h2 = hl[lane * HS + 4 * c + 2];
        float h3 = hl[lane * HS + 4 * c + 3];
        const float* __restrict__ w = Wl + c * 256 + col0;
#pragma unroll
        for (int j = 0; j < 16; ++j) {
            acc[j] = fmaf(h0, w[j], acc[j]);
            acc[j] = fmaf(h1, w[64 + j], acc[j]);
            acc[j] = fmaf(h2, w[128 + j], acc[j]);
            acc[j] = fmaf(h3, w[192 + j], acc[j]);
        }
    }
    __syncthreads();
    {
        const float4* __restrict__ s4 = (const float4*)WsD;
        float4* __restrict__ d4 = (float4*)Wl;
        for (int i = tid; i < 1024; i += 256) d4[i] = s4[i];
    }
    __syncthreads();

    // ---- Q0-S + store ----
#pragma unroll
    for (int j = 0; j < 16; ++j) acc2[j] = bs[col0 + j];
    for (int c = 0; c < 16; ++c) {
        float h0 = hl[lane * HS + 4 * c + 0];
        float h1 = hl[lane * HS + 4 * c + 1];
        float h2 = hl[lane * HS + 4 * c + 2];
        float h3 = hl[lane * HS + 4 * c + 3];
        const float* __restrict__ w = Wl + c * 256 + col0;
#pragma unroll
        for (int j = 0; j < 16; ++j) {
            acc2[j] = fmaf(h0, w[j], acc2[j]);
            acc2[j] = fmaf(h1, w[64 + j], acc2[j]);
            acc2[j] = fmaf(h2, w[128 + j], acc2[j]);
            acc2[j] = fmaf(h3, w[192 + j], acc2[j]);
        }
    }
    if (act) {
        float4* __restrict__ qp = (float4*)(Qout + (size_t)n * 128 + col0 * 2);
#pragma unroll
        for (int q = 0; q < 8; ++q)
            qp[q] = make_float4(acc[q * 2], acc2[q * 2], acc[q * 2 + 1], acc2[q * 2 + 1]);
    }
}

// ---------------------------------------------------------------------------
// Gate projections for one CGConv layer: P (src half, packed bf16) and
// Q (dst half + bias, fp32 (qf,qs) pairs).
// R13: same 4-way column split as premlp; h tile staged coalesced into LDS.
// ---------------------------------------------------------------------------
__global__ __launch_bounds__(256, 4) void pjq_kernel(
    const float* __restrict__ h,
    const float* __restrict__ Wf, const float* __restrict__ Ws,
    const float* __restrict__ bfv, const float* __restrict__ bsv,
    unsigned int* __restrict__ P, float* __restrict__ Q, int N)
{
    __shared__ __align__(16) float Wl[4096];
    __shared__ float hl[64 * HS];
    const int tid = threadIdx.x;
    const int lane = tid & 63;
    const int col0 = (tid >> 6) * 16;
    const int base = blockIdx.x * 64;
    const int n = base + lane;
    const bool act = (n < N);

    float acc[16], acc2[16];

    // stage h tile (coalesced global read, padded LDS write) + WfS
    for (int q = tid; q < 1024; q += 256) {
        int r = q >> 4, c4 = q & 15;
        int rr = base + r; rr = (rr < N) ? rr : (N - 1);
        float4 v = ((const float4*)(h + (size_t)rr * 64))[c4];
        float* dp = hl + r * HS + c4 * 4;
        dp[0] = v.x; dp[1] = v.y; dp[2] = v.z; dp[3] = v.w;
    }
    {
        const float4* __restrict__ s4 = (const float4*)(Wf + 64 * 64);
        float4* __restrict__ d4 = (float4*)Wl;
        for (int i = tid; i < 1024; i += 256) d4[i] = s4[i];
    }
    __syncthreads();

    // ---- P-F ----
#pragma unroll
    for (int j = 0; j < 16; ++j) acc[j] = 0.f;
    for (int c = 0; c < 16; ++c) {
        float h0 = hl[lane * HS + 4 * c + 0];
        float h1 = hl[lane * HS + 4 * c + 1];
        float h2 = hl[lane * HS + 4 * c + 2];
        float h3 = hl[lane * HS + 4 * c + 3];
        const float* __restrict__ w = Wl + c * 256 + col0;
#pragma unroll
        for (int j = 0; j < 16; ++j) {
            acc[j] = fmaf(h0, w[j], acc[j]);
            acc[j] = fmaf(h1, w[64 + j], acc[j]);
            acc[j] = fmaf(h2, w[128 + j], acc[j]);
            acc[j] = fmaf(h3, w[192 + j], acc[j]);
        }
    }
    __syncthreads();
    {
        const float4* __restrict__ s4 = (const float4*)(Ws + 64 * 64);
        float4* __restrict__ d4 = (float4*)Wl;
        for (int i = tid; i < 1024; i += 256) d4[i] = s4[i];
    }
    __syncthreads();

    // ---- P-S + store ----
#pragma unroll
    for (int j = 0; j < 16; ++j) acc2[j] = 0.f;
    for (int c = 0; c < 16; ++c) {
        float h0 = hl[lane * HS + 4 * c + 0];
        float h1 = hl[lane * HS + 4 * c + 1];
        float h2 = hl[lane * HS + 4 * c + 2];
        float h3 = hl[lane * HS + 4 * c + 3];
        const float* __restrict__ w = Wl + c * 256 + col0;
#pragma unroll
        for (int j = 0; j < 16; ++j) {
            acc2[j] = fmaf(h0, w[j], acc2[j]);
            acc2[j] = fmaf(h1, w[64 + j], acc2[j]);
            acc2[j] = fmaf(h2, w[128 + j], acc2[j]);
            acc2[j] = fmaf(h3, w[192 + j], acc2[j]);
        }
    }
    if (act) {
        uint4* __restrict__ pp = (uint4*)(P + (size_t)n * 64 + col0);
#pragma unroll
        for (int q = 0; q < 4; ++q) {
            uint4 pk;
            pk.x = f2bf_rne(acc[q * 4])     | (f2bf_rne(acc2[q * 4]) << 16);
            pk.y = f2bf_rne(acc[q * 4 + 1]) | (f2bf_rne(acc2[q * 4 + 1]) << 16);
            pk.z = f2bf_rne(acc[q * 4 + 2]) | (f2bf_rne(acc2[q * 4 + 2]) << 16);
            pk.w = f2bf_rne(acc[q * 4 + 3]) | (f2bf_rne(acc2[q * 4 + 3]) << 16);
            pp[q] = pk;
        }
    }
    __syncthreads();
    {
        const float4* __restrict__ s4 = (const float4*)Wf;
        float4* __restrict__ d4 = (float4*)Wl;
        for (int i = tid; i < 1024; i += 256) d4[i] = s4[i];
    }
    __syncthreads();

    // ---- Q-F ----
#pragma unroll
    for (int j = 0; j < 16; ++j) acc[j] = bfv[col0 + j];
    for (int c = 0; c < 16; ++c) {
        float h0 = hl[lane * HS + 4 * c + 0];
        float h1 = hl[lane * HS + 4 * c + 1];
        float h2 = hl[lane * HS + 4 * c + 2];
        float h3 = hl[lane * HS + 4 * c + 3];
        const float* __restrict__ w = Wl + c * 256 + col0;
#pragma unroll
        for (int j = 0; j < 16; ++j) {
            acc[j] = fmaf(h0, w[j], acc[j]);
            acc[j] = fmaf(h1, w[64 + j], acc[j]);
            acc[j] = fmaf(h2, w[128 + j], acc[j]);
            acc[j] = fmaf(h3, w[192 + j], acc[j]);
        }
    }
    __syncthreads();
    {
        const float4* __restrict__ s4 = (const float4*)Ws;
        float4* __restrict__ d4 = (float4*)Wl;
        for (int i = tid; i < 1024; i += 256) d4[i] = s4[i];
    }
    __syncthreads();

    // ---- Q-S + store ----
#pragma unroll
    for (int j = 0; j < 16; ++j) acc2[j] = bsv[col0 + j];
    for (int c = 0; c < 16; ++c) {
        float h0 = hl[lane * HS + 4 * c + 0];
        float h1 = hl[lane * HS + 4 * c + 1];
        float h2 = hl[lane * HS + 4 * c + 2];
        float h3 = hl[lane * HS + 4 * c + 3];
        const float* __restrict__ w = Wl + c * 256 + col0;
#pragma unroll
        for (int j = 0; j < 16; ++j) {
            acc2[j] = fmaf(h0, w[j], acc2[j]);
            acc2[j] = fmaf(h1, w[64 + j], acc2[j]);
            acc2[j] = fmaf(h2, w[128 + j], acc2[j]);
            acc2[j] = fmaf(h3, w[192 + j], acc2[j]);
        }
    }
    if (act) {
        float4* __restrict__ qp = (float4*)(Q + (size_t)n * 128 + col0 * 2);
#pragma unroll
        for (int q = 0; q < 8; ++q)
            qp[q] = make_float4(acc[q * 2], acc2[q * 2], acc[q * 2 + 1], acc2[q * 2 + 1]);
    }
}

// ---------------------------------------------------------------------------
// In-degree histogram (int)
// ---------------------------------------------------------------------------
__global__ __launch_bounds__(256) void deg_kernel(
    const int* __restrict__ dst, int* __restrict__ deg, int E)
{
    int e = blockIdx.x * blockDim.x + threadIdx.x;
    if (e < E) atomicAdd(&deg[dst[e]], 1);
}

// ---------------------------------------------------------------------------
// Three-phase exclusive scan over deg -> rowptr, cursor
// ---------------------------------------------------------------------------
__global__ __launch_bounds__(1024) void scanA_kernel(
    const int* __restrict__ deg, int* __restrict__ iscan,
    int* __restrict__ bsum, int N)
{
    __shared__ int lds[1024];
    int tid = threadIdx.x;
    int gid = blockIdx.x * 1024 + tid;
    int v = (gid < N) ? deg[gid] : 0;
    lds[tid] = v; __syncthreads();
    for (int off = 1; off < 1024; off <<= 1) {
        int t = (tid >= off) ? lds[tid - off] : 0;
        __syncthreads();
        lds[tid] += t;
        __syncthreads();
    }
    if (gid < N) iscan[gid] = lds[tid];
    if (tid == 1023) bsum[blockIdx.x] = lds[1023];
}

__global__ __launch_bounds__(128) void scanB_kernel(
    const int* __restrict__ bsum, int* __restrict__ boff, int nb)
{
    __shared__ int lds[128];
    int t = threadIdx.x;
    int v = (t < nb) ? bsum[t] : 0;
    lds[t] = v; __syncthreads();
    for (int off = 1; off < 128; off <<= 1) {
        int u = (t >= off) ? lds[t - off] : 0;
        __syncthreads();
        lds[t] += u;
        __syncthreads();
    }
    if (t < nb) boff[t] = lds[t] - v;  // exclusive
}

__global__ __launch_bounds__(256) void scanC_kernel(
    const int* __restrict__ iscan, const int* __restrict__ boff,
    const int* __restrict__ deg,
    int* __restrict__ rowptr, int* __restrict__ cursor, int N)
{
    int i = blockIdx.x * blockDim.x + threadIdx.x;
    if (i >= N) return;
    int incl = iscan[i] + boff[i >> 10];
    rowptr[i + 1] = incl;
    cursor[i] = incl - deg[i];
    if (i == 0) rowptr[0] = 0;
}

// ---------------------------------------------------------------------------
// Edge scatter into CSR order, packed (src, ea) int2
// ---------------------------------------------------------------------------
__global__ __launch_bounds__(256) void escatter_kernel(
    const int* __restrict__ src, const int* __restrict__ dst,
    const float* __restrict__ ea, int* __restrict__ cursor,
    int2* __restrict__ e_se, int E)
{
    int e = blockIdx.x * blockDim.x + threadIdx.x;
    if (e >= E) return;
    int pos = atomicAdd(&cursor[dst[e]], 1);
    e_se[pos] = make_int2(src[e], __float_as_int(ea[e]));
}

// ---------------------------------------------------------------------------
// CGConv edge pass. One wave per node, lane = dim. Q precomputed (R12).
// ---------------------------------------------------------------------------
__global__ __launch_bounds__(256) void edge_kernel(
    const float* __restrict__ h, const int* __restrict__ rowptr,
    const int2* __restrict__ e_se,
    const unsigned int* __restrict__ P,
    const float* __restrict__ Q,
    const float* __restrict__ Wf, const float* __restrict__ Ws,
    float* __restrict__ hout)
{
    int n = blockIdx.x * 4 + (threadIdx.x >> 6);   // grid exactly covers GN
    int d = threadIdx.x & 63;

    const float2 qv = ((const float2*)Q)[(size_t)n * 64 + d];
    float qf = qv.x, qs = qv.y;
    float wf = Wf[128 * 64 + d];
    float ws = Ws[128 * 64 + d];

    size_t idx = (size_t)n * 64 + d;
    float hres = h[idx];

    int rb = rowptr[n], re = rowptr[n + 1];
    float agg = 0.f;
#pragma unroll 8
    for (int p = rb; p < re; ++p) {
        int2 se = e_se[p];         // wave-uniform 8B load
        int s = se.x;
        float ea = __int_as_float(se.y);
        unsigned int pv = P[(size_t)s * 64 + d];   // gathered dword (256B/wave)
        float pf = __uint_as_float(pv << 16);
        float psv = __uint_as_float(pv & 0xffff0000u);
        float xF = fmaf(ea, wf, qf + pf);
        float xS = fmaf(ea, ws, qs + psv);
        float sig = __builtin_amdgcn_rcpf(1.f + __expf(-xF));
        float t = __expf(-fabsf(xS));
        float sp = fmaxf(xS, 0.f) + __logf(1.f + t);
        agg = fmaf(sig, sp, agg);
    }

    float inv = 1.f / (float)max(re - rb, 1);
    hout[idx] = fmaxf(hres + agg * inv, 0.f);
}

// ---------------------------------------------------------------------------
// Graph segment starts: bm sorted; gstart[b] = first node of graph b.
// ---------------------------------------------------------------------------
__global__ __launch_bounds__(256) void gstart_kernel(
    const int* __restrict__ bm, int* __restrict__ gstart, int N)
{
    int i = blockIdx.x * blockDim.x + threadIdx.x;
    if (i >= N) return;
    int b = bm[i];
    int prev = (i == 0) ? -1 : bm[i - 1];
    for (int g = prev + 1; g <= b; ++g) gstart[g] = i;
    if (i == N - 1)
        for (int g = b + 1; g <= GB; ++g) gstart[g] = N;
}

// ---------------------------------------------------------------------------
// Segmented mean pool: one block per graph, no atomics.
// ---------------------------------------------------------------------------
__global__ __launch_bounds__(256) void pool_seg_kernel(
    const float* __restrict__ h, const int* __restrict__ gstart,
    float* __restrict__ g)
{
    int b = blockIdx.x;
    int s = gstart[b], e = gstart[b + 1];
    int d = threadIdx.x & 63;
    int w = threadIdx.x >> 6;
    float acc = 0.f;
    for (int n = s + w; n < e; n += 4)
        acc += h[(size_t)n * 64 + d];
    __shared__ float lds[256];
    lds[threadIdx.x] = acc;
    __syncthreads();
    if (w == 0) {
        acc = lds[d] + lds[64 + d] + lds[128 + d] + lds[192 + d];
        g[b * 64 + d] = acc / fmaxf((float)(e - s), 1.f);
    }
}

// ---------------------------------------------------------------------------
// Fused post-MLP (3 relu layers) + final dot + bias. One wave per graph.
// ---------------------------------------------------------------------------
__global__ __launch_bounds__(256) void postmlp_kernel(
    const float* __restrict__ g,
    const float* __restrict__ W0, const float* __restrict__ b0,
    const float* __restrict__ W1, const float* __restrict__ b1,
    const float* __restrict__ W2, const float* __restrict__ b2,
    const float* __restrict__ Wfin, const float* __restrict__ bfin,
    float* __restrict__ out)
{
    int b = blockIdx.x * 4 + (threadIdx.x >> 6);   // 32 blocks x 4 waves = 128
    int d = threadIdx.x & 63;
    float h = g[(size_t)b * 64 + d];

    float acc = b0[d];
#pragma unroll
    for (int k = 0; k < 64; ++k)
        acc = fmaf(__shfl(h, k, 64), W0[k * 64 + d], acc);
    h = fmaxf(acc, 0.f);

    acc = b1[d];
#pragma unroll
    for (int k = 0; k < 64; ++k)
        acc = fmaf(__shfl(h, k, 64), W1[k * 64 + d], acc);
    h = fmaxf(acc, 0.f);

    acc = b2[d];
#pragma unroll
    for (int k = 0; k < 64; ++k)
        acc = fmaf(__shfl(h, k, 64), W2[k * 64 + d], acc);
    h = fmaxf(acc, 0.f);

    float v = h * Wfin[d];
#pragma unroll
    for (int off = 32; off >= 1; off >>= 1)
        v += __shfl_xor(v, off, 64);
    if (d == 0) out[b] = v + bfin[0];
}

extern "C" void kernel_launch(void* const* d_in, const int* in_sizes, int n_in,
                              void* d_out, int out_size, void* d_ws, size_t ws_size,
                              hipStream_t stream)
{
    const float* X      = (const float*)d_in[0];
    const int*   eidx   = (const int*)d_in[1];
    const float* ea     = (const float*)d_in[3];
    const int*   bm     = (const int*)d_in[4];
    const float* pre_W0 = (const float*)d_in[5];
    const float* pre_b0 = (const float*)d_in[6];
    const float* pre_W1 = (const float*)d_in[7];
    const float* pre_b1 = (const float*)d_in[8];
    const float* pre_W2 = (const float*)d_in[9];
    const float* pre_b2 = (const float*)d_in[10];
    const float* cg_Wf  = (const float*)d_in[11];
    const float* cg_bf  = (const float*)d_in[12];
    const float* cg_Ws  = (const float*)d_in[13];
    const float* cg_bs  = (const float*)d_in[14];
    const float* post_W0 = (const float*)d_in[15];
    const float* post_b0 = (const float*)d_in[16];
    const float* post_W1 = (const float*)d_in[17];
    const float* post_b1 = (const float*)d_in[18];
    const float* post_W2 = (const float*)d_in[19];
    const float* post_b2 = (const float*)d_in[20];
    const float* post_Wf = (const float*)d_in[21];
    const float* post_bf = (const float*)d_in[22];

    const int* src = eidx;
    const int* dst = eidx + GE;

    // ---- workspace carve-up ----
    const size_t N64 = (size_t)GN * 64;
    float* hA    = (float*)d_ws;            // N*64
    float* hB    = hA + N64;                // N*64
    unsigned int* P = (unsigned int*)(hB + N64);  // N*64 packed bf16x2
    int* deg_i   = (int*)(P + N64);         // N
    int* iscan   = deg_i + GN;              // N
    int* bsum    = iscan + GN;              // 128
    int* boff    = bsum + 128;              // 128
    int* rowptr  = boff + 128;              // N+2 (padded so e_se is 8B-aligned)
    int* cursor  = rowptr + GN + 2;         // N
    int2* e_se   = (int2*)(cursor + GN);    // E int2 (8B-aligned)
    int* gstart  = (int*)(e_se + GE);       // B+1
    float* g0    = (float*)(gstart + GB + 1); // B*64 (8192 floats, keeps 8B align)
    float* Q     = g0 + (size_t)GB * 64;    // N*128 fp32 (qf,qs) pairs

    const int TPB = 256;
    int gridE  = (GE + TPB - 1) / TPB;
    int gridN  = (GN + TPB - 1) / TPB;         // 391 (lane=node grid)
    int gridP  = (GN + 63) / 64;               // 1563 (col-split dense grid)
    int gridND = ((GN * 64) + TPB - 1) / TPB;  // 25000 (edge grid)
    int scanBlocks = (GN + 1023) / 1024;       // 98

    // per-layer weight pointers
    const float* Wf0 = cg_Wf;
    const float* Ws0 = cg_Ws;
    const float* Wf1 = cg_Wf + (size_t)1 * GZ * GD;
    const float* Ws1 = cg_Ws + (size_t)1 * GZ * GD;
    const float* Wf2 = cg_Wf + (size_t)2 * GZ * GD;
    const float* Ws2 = cg_Ws + (size_t)2 * GZ * GD;

    // fused pre-MLP (col-split) + P0 + Q0
    premlp_kernel<<<gridP, TPB, 0, stream>>>(
        X, pre_W0, pre_b0, pre_W1, pre_b1, pre_W2, pre_b2,
        Wf0, Ws0, Ws0 + 64 * 64, Wf0 + 64 * 64, cg_bf, cg_bs,
        hA, P, Q, GN);

    // degree + CSR build
    hipMemsetAsync(deg_i, 0, GN * sizeof(int), stream);
    deg_kernel<<<gridE, TPB, 0, stream>>>(dst, deg_i, GE);
    scanA_kernel<<<scanBlocks, 1024, 0, stream>>>(deg_i, iscan, bsum, GN);
    scanB_kernel<<<1, 128, 0, stream>>>(bsum, boff, scanBlocks);
    scanC_kernel<<<gridN, TPB, 0, stream>>>(iscan, boff, deg_i, rowptr, cursor, GN);
    escatter_kernel<<<gridE, TPB, 0, stream>>>(src, dst, ea, cursor, e_se, GE);

    // graph segment starts (bm sorted)
    gstart_kernel<<<gridN, TPB, 0, stream>>>(bm, gstart, GN);

    // CGConv layers: lean edge pass + fused P/Q projection for next layer
    edge_kernel<<<gridND, TPB, 0, stream>>>(
        hA, rowptr, e_se, P, Q, Wf0, Ws0, hB);
    pjq_kernel<<<gridP, TPB, 0, stream>>>(
        hB, Wf1, Ws1, cg_bf + GD, cg_bs + GD, P, Q, GN);
    edge_kernel<<<gridND, TPB, 0, stream>>>(
        hB, rowptr, e_se, P, Q, Wf1, Ws1, hA);
    pjq_kernel<<<gridP, TPB, 0, stream>>>(
        hA, Wf2, Ws2, cg_bf + 2 * GD, cg_bs + 2 * GD, P, Q, GN);
    edge_kernel<<<gridND, TPB, 0, stream>>>(
        hA, rowptr, e_se, P, Q, Wf2, Ws2, hB);

    // segmented mean pool (no atomics)
    pool_seg_kernel<<<GB, TPB, 0, stream>>>(hB, gstart, g0);

    // fused post-MLP + final projection
    postmlp_kernel<<<GB / 4, TPB, 0, stream>>>(
        g0, post_W0, post_b0, post_W1, post_b1, post_W2, post_b2,
        post_Wf, post_bf, (float*)d_out);
}

// Round 4
// 884.024 us; speedup vs baseline: 1.3447x; 1.0121x over previous
//
#include <hip/hip_runtime.h>
#include <hip/hip_bf16.h>
#include <math.h>

// Problem constants (fixed by the reference)
#define GN 100000   // nodes
#define GE 1200000  // edges
#define GB 128      // graphs
#define GF 92       // raw features
#define GD 64       // hidden dim
#define GL 3        // CGConv layers
#define GZ 129      // 2*D+1

#define HS 65       // padded LDS h-tile stride (bank = (lane + k) & 31, 2-way alias = free)

// round-to-nearest-even fp32 -> bf16 (returned in low 16 bits)
__device__ __forceinline__ unsigned int f2bf_rne(float x)
{
    unsigned int u = __float_as_uint(x);
    u += 0x7fffu + ((u >> 16) & 1u);
    return u >> 16;
}

// ---------------------------------------------------------------------------
// Fused pre-MLP (3 layers) + P0 + Q0.
// R13: 4-way column split (wave = 16-col slice), weights + h tile in LDS.
// R14: register-block R=2 nodes/thread (block tile = 128 nodes). The 16
// uniform weight ds_read_b128 per c-iter now feed 128 FMAs instead of 64 --
// total LDS instructions drop to 0.6x (LDS-issue was the measured limiter:
// VALUBusy pinned at 30% across 15%->33% occupancy).
// Accumulation order per output element unchanged (bitwise-same results).
// ---------------------------------------------------------------------------
__global__ __launch_bounds__(256, 2) void premlp_kernel(
    const float* __restrict__ X,
    const float* __restrict__ W0, const float* __restrict__ b0,
    const float* __restrict__ W1, const float* __restrict__ b1,
    const float* __restrict__ W2, const float* __restrict__ b2,
    const float* __restrict__ WfD, const float* __restrict__ WsD,   // rows 0..63
    const float* __restrict__ WfS, const float* __restrict__ WsS,   // rows 64..127
    const float* __restrict__ bf, const float* __restrict__ bs,
    float* __restrict__ hout, unsigned int* __restrict__ Pout,
    float* __restrict__ Qout, int N)
{
    __shared__ __align__(16) float Wl[5888];    // 23 KB weight stage (W0 needs it all)
    __shared__ float hl[128 * HS];              // 33.3 KB padded h tile (128 nodes)
    const int tid = threadIdx.x;
    const int lane = tid & 63;
    const int col0 = (tid >> 6) * 16;           // this wave's column slice
    const int base = blockIdx.x * 128;
    const int n0 = base + lane;
    const int n1 = base + 64 + lane;
    const int nn0 = (n0 < N) ? n0 : (N - 1);
    const int nn1 = (n1 < N) ? n1 : (N - 1);
    const bool act0 = (n0 < N), act1 = (n1 < N);

    float a0[16], a1[16], s0[16], s1[16];

    // ---- stage W0 (92x64 = 1472 float4) ----
    {
        const float4* __restrict__ s4 = (const float4*)W0;
        float4* __restrict__ d4 = (float4*)Wl;
        for (int i = tid; i < 1472; i += 256) d4[i] = s4[i];
    }
    __syncthreads();

    // ---- layer 0: K=92 ----
#pragma unroll
    for (int j = 0; j < 16; ++j) { a0[j] = b0[col0 + j]; a1[j] = a0[j]; }
    {
        const float4* __restrict__ r40 = (const float4*)(X + (size_t)nn0 * GF);
        const float4* __restrict__ r41 = (const float4*)(X + (size_t)nn1 * GF);
        for (int c = 0; c < 23; ++c) {
            float4 v0 = r40[c];
            float4 v1 = r41[c];
            const float* __restrict__ w = Wl + c * 256 + col0;
#pragma unroll
            for (int j = 0; j < 16; ++j) {
                float wa = w[j], wb = w[64 + j], wc = w[128 + j], wd = w[192 + j];
                a0[j] = fmaf(v0.x, wa, a0[j]);
                a0[j] = fmaf(v0.y, wb, a0[j]);
                a0[j] = fmaf(v0.z, wc, a0[j]);
                a0[j] = fmaf(v0.w, wd, a0[j]);
                a1[j] = fmaf(v1.x, wa, a1[j]);
                a1[j] = fmaf(v1.y, wb, a1[j]);
                a1[j] = fmaf(v1.z, wc, a1[j]);
                a1[j] = fmaf(v1.w, wd, a1[j]);
            }
        }
    }
    __syncthreads();    // all Wl reads done
#pragma unroll
    for (int j = 0; j < 16; ++j) {
        hl[lane * HS + col0 + j] = fmaxf(a0[j], 0.f);
        hl[(64 + lane) * HS + col0 + j] = fmaxf(a1[j], 0.f);
    }
    {
        const float4* __restrict__ s4 = (const float4*)W1;
        float4* __restrict__ d4 = (float4*)Wl;
        for (int i = tid; i < 1024; i += 256) d4[i] = s4[i];
    }
    __syncthreads();

    // ---- layer 1 ----
#pragma unroll
    for (int j = 0; j < 16; ++j) { a0[j] = b1[col0 + j]; a1[j] = a0[j]; }
    for (int c = 0; c < 16; ++c) {
        float h0 = hl[lane * HS + 4 * c + 0];
        float h1 = hl[lane * HS + 4 * c + 1];
        float h2 = hl[lane * HS + 4 * c + 2];
        float h3 = hl[lane * HS + 4 * c + 3];
        float g0 = hl[(64 + lane) * HS + 4 * c + 0];
        float g1 = hl[(64 + lane) * HS + 4 * c + 1];
        float g2 = hl[(64 + lane) * HS + 4 * c + 2];
        float g3 = hl[(64 + lane) * HS + 4 * c + 3];
        const float* __restrict__ w = Wl + c * 256 + col0;
#pragma unroll
        for (int j = 0; j < 16; ++j) {
            float wa = w[j], wb = w[64 + j], wc = w[128 + j], wd = w[192 + j];
            a0[j] = fmaf(h0, wa, a0[j]);
            a0[j] = fmaf(h1, wb, a0[j]);
            a0[j] = fmaf(h2, wc, a0[j]);
            a0[j] = fmaf(h3, wd, a0[j]);
            a1[j] = fmaf(g0, wa, a1[j]);
            a1[j] = fmaf(g1, wb, a1[j]);
            a1[j] = fmaf(g2, wc, a1[j]);
            a1[j] = fmaf(g3, wd, a1[j]);
        }
    }
    __syncthreads();
#pragma unroll
    for (int j = 0; j < 16; ++j) {
        hl[lane * HS + col0 + j] = fmaxf(a0[j], 0.f);
        hl[(64 + lane) * HS + col0 + j] = fmaxf(a1[j], 0.f);
    }
    {
        const float4* __restrict__ s4 = (const float4*)W2;
        float4* __restrict__ d4 = (float4*)Wl;
        for (int i = tid; i < 1024; i += 256) d4[i] = s4[i];
    }
    __syncthreads();

    // ---- layer 2 ----
#pragma unroll
    for (int j = 0; j < 16; ++j) { a0[j] = b2[col0 + j]; a1[j] = a0[j]; }
    for (int c = 0; c < 16; ++c) {
        float h0 = hl[lane * HS + 4 * c + 0];
        float h1 = hl[lane * HS + 4 * c + 1];
        float h2 = hl[lane * HS + 4 * c + 2];
        float h3 = hl[lane * HS + 4 * c + 3];
        float g0 = hl[(64 + lane) * HS + 4 * c + 0];
        float g1 = hl[(64 + lane) * HS + 4 * c + 1];
        float g2 = hl[(64 + lane) * HS + 4 * c + 2];
        float g3 = hl[(64 + lane) * HS + 4 * c + 3];
        const float* __restrict__ w = Wl + c * 256 + col0;
#pragma unroll
        for (int j = 0; j < 16; ++j) {
            float wa = w[j], wb = w[64 + j], wc = w[128 + j], wd = w[192 + j];
            a0[j] = fmaf(h0, wa, a0[j]);
            a0[j] = fmaf(h1, wb, a0[j]);
            a0[j] = fmaf(h2, wc, a0[j]);
            a0[j] = fmaf(h3, wd, a0[j]);
            a1[j] = fmaf(g0, wa, a1[j]);
            a1[j] = fmaf(g1, wb, a1[j]);
            a1[j] = fmaf(g2, wc, a1[j]);
            a1[j] = fmaf(g3, wd, a1[j]);
        }
    }
    __syncthreads();
#pragma unroll
    for (int j = 0; j < 16; ++j) {
        hl[lane * HS + col0 + j] = fmaxf(a0[j], 0.f);
        hl[(64 + lane) * HS + col0 + j] = fmaxf(a1[j], 0.f);
    }
    if (act0) {
        float4* __restrict__ op = (float4*)(hout + (size_t)n0 * 64 + col0);
#pragma unroll
        for (int q = 0; q < 4; ++q)
            op[q] = make_float4(fmaxf(a0[q * 4], 0.f), fmaxf(a0[q * 4 + 1], 0.f),
                                fmaxf(a0[q * 4 + 2], 0.f), fmaxf(a0[q * 4 + 3], 0.f));
    }
    if (act1) {
        float4* __restrict__ op = (float4*)(hout + (size_t)n1 * 64 + col0);
#pragma unroll
        for (int q = 0; q < 4; ++q)
            op[q] = make_float4(fmaxf(a1[q * 4], 0.f), fmaxf(a1[q * 4 + 1], 0.f),
                                fmaxf(a1[q * 4 + 2], 0.f), fmaxf(a1[q * 4 + 3], 0.f));
    }
    {
        const float4* __restrict__ s4 = (const float4*)WfS;
        float4* __restrict__ d4 = (float4*)Wl;
        for (int i = tid; i < 1024; i += 256) d4[i] = s4[i];
    }
    __syncthreads();

    // ---- P0-F ----
#pragma unroll
    for (int j = 0; j < 16; ++j) { a0[j] = 0.f; a1[j] = 0.f; }
    for (int c = 0; c < 16; ++c) {
        float h0 = hl[lane * HS + 4 * c + 0];
        float h1 = hl[lane * HS + 4 * c + 1];
        float h2 = hl[lane * HS + 4 * c + 2];
        float h3 = hl[lane * HS + 4 * c + 3];
        float g0 = hl[(64 + lane) * HS + 4 * c + 0];
        float g1 = hl[(64 + lane) * HS + 4 * c + 1];
        float g2 = hl[(64 + lane) * HS + 4 * c + 2];
        float g3 = hl[(64 + lane) * HS + 4 * c + 3];
        const float* __restrict__ w = Wl + c * 256 + col0;
#pragma unroll
        for (int j = 0; j < 16; ++j) {
            float wa = w[j], wb = w[64 + j], wc = w[128 + j], wd = w[192 + j];
            a0[j] = fmaf(h0, wa, a0[j]);
            a0[j] = fmaf(h1, wb, a0[j]);
            a0[j] = fmaf(h2, wc, a0[j]);
            a0[j] = fmaf(h3, wd, a0[j]);
            a1[j] = fmaf(g0, wa, a1[j]);
            a1[j] = fmaf(g1, wb, a1[j]);
            a1[j] = fmaf(g2, wc, a1[j]);
            a1[j] = fmaf(g3, wd, a1[j]);
        }
    }
    __syncthreads();
    {
        const float4* __restrict__ s4 = (const float4*)WsS;
        float4* __restrict__ d4 = (float4*)Wl;
        for (int i = tid; i < 1024; i += 256) d4[i] = s4[i];
    }
    __syncthreads();

    // ---- P0-S + store ----
#pragma unroll
    for (int j = 0; j < 16; ++j) { s0[j] = 0.f; s1[j] = 0.f; }
    for (int c = 0; c < 16; ++c) {
        float h0 = hl[lane * HS + 4 * c + 0];
        float h1 = hl[lane * HS + 4 * c + 1];
        float h2 = hl[lane * HS + 4 * c + 2];
        float h3 = hl[lane * HS + 4 * c + 3];
        float g0 = hl[(64 + lane) * HS + 4 * c + 0];
        float g1 = hl[(64 + lane) * HS + 4 * c + 1];
        float g2 = hl[(64 + lane) * HS + 4 * c + 2];
        float g3 = hl[(64 + lane) * HS + 4 * c + 3];
        const float* __restrict__ w = Wl + c * 256 + col0;
#pragma unroll
        for (int j = 0; j < 16; ++j) {
            float wa = w[j], wb = w[64 + j], wc = w[128 + j], wd = w[192 + j];
            s0[j] = fmaf(h0, wa, s0[j]);
            s0[j] = fmaf(h1, wb, s0[j]);
            s0[j] = fmaf(h2, wc, s0[j]);
            s0[j] = fmaf(h3, wd, s0[j]);
            s1[j] = fmaf(g0, wa, s1[j]);
            s1[j] = fmaf(g1, wb, s1[j]);
            s1[j] = fmaf(g2, wc, s1[j]);
            s1[j] = fmaf(g3, wd, s1[j]);
        }
    }
    if (act0) {
        uint4* __restrict__ pp = (uint4*)(Pout + (size_t)n0 * 64 + col0);
#pragma unroll
        for (int q = 0; q < 4; ++q) {
            uint4 pk;
            pk.x = f2bf_rne(a0[q * 4])     | (f2bf_rne(s0[q * 4]) << 16);
            pk.y = f2bf_rne(a0[q * 4 + 1]) | (f2bf_rne(s0[q * 4 + 1]) << 16);
            pk.z = f2bf_rne(a0[q * 4 + 2]) | (f2bf_rne(s0[q * 4 + 2]) << 16);
            pk.w = f2bf_rne(a0[q * 4 + 3]) | (f2bf_rne(s0[q * 4 + 3]) << 16);
            pp[q] = pk;
        }
    }
    if (act1) {
        uint4* __restrict__ pp = (uint4*)(Pout + (size_t)n1 * 64 + col0);
#pragma unroll
        for (int q = 0; q < 4; ++q) {
            uint4 pk;
            pk.x = f2bf_rne(a1[q * 4])     | (f2bf_rne(s1[q * 4]) << 16);
            pk.y = f2bf_rne(a1[q * 4 + 1]) | (f2bf_rne(s1[q * 4 + 1]) << 16);
            pk.z = f2bf_rne(a1[q * 4 + 2]) | (f2bf_rne(s1[q * 4 + 2]) << 16);
            pk.w = f2bf_rne(a1[q * 4 + 3]) | (f2bf_rne(s1[q * 4 + 3]) << 16);
            pp[q] = pk;
        }
    }
    __syncthreads();
    {
        const float4* __restrict__ s4 = (const float4*)WfD;
        float4* __restrict__ d4 = (float4*)Wl;
        for (int i = tid; i < 1024; i += 256) d4[i] = s4[i];
    }
    __syncthreads();

    // ---- Q0-F ----
#pragma unroll
    for (int j = 0; j < 16; ++j) { a0[j] = bf[col0 + j]; a1[j] = a0[j]; }
    for (int c = 0; c < 16; ++c) {
        float h0 = hl[lane * HS + 4 * c + 0];
        float h1 = hl[lane * HS + 4 * c + 1];
        float h2 = hl[lane * HS + 4 * c + 2];
        float h3 = hl[lane * HS + 4 * c + 3];
        float g0 = hl[(64 + lane) * HS + 4 * c + 0];
        float g1 = hl[(64 + lane) * HS + 4 * c + 1];
        float g2 = hl[(64 + lane) * HS + 4 * c + 2];
        float g3 = hl[(64 + lane) * HS + 4 * c + 3];
        const float* __restrict__ w = Wl + c * 256 + col0;
#pragma unroll
        for (int j = 0; j < 16; ++j) {
            float wa = w[j], wb = w[64 + j], wc = w[128 + j], wd = w[192 + j];
            a0[j] = fmaf(h0, wa, a0[j]);
            a0[j] = fmaf(h1, wb, a0[j]);
            a0[j] = fmaf(h2, wc, a0[j]);
            a0[j] = fmaf(h3, wd, a0[j]);
            a1[j] = fmaf(g0, wa, a1[j]);
            a1[j] = fmaf(g1, wb, a1[j]);
            a1[j] = fmaf(g2, wc, a1[j]);
            a1[j] = fmaf(g3, wd, a1[j]);
        }
    }
    __syncthreads();
    {
        const float4* __restrict__ s4 = (const float4*)WsD;
        float4* __restrict__ d4 = (float4*)Wl;
        for (int i = tid; i < 1024; i += 256) d4[i] = s4[i];
    }
    __syncthreads();

    // ---- Q0-S + store ----
#pragma unroll
    for (int j = 0; j < 16; ++j) { s0[j] = bs[col0 + j]; s1[j] = s0[j]; }
    for (int c = 0; c < 16; ++c) {
        float h0 = hl[lane * HS + 4 * c + 0];
        float h1 = hl[lane * HS + 4 * c + 1];
        float h2 = hl[lane * HS + 4 * c + 2];
        float h3 = hl[lane * HS + 4 * c + 3];
        float g0 = hl[(64 + lane) * HS + 4 * c + 0];
        float g1 = hl[(64 + lane) * HS + 4 * c + 1];
        float g2 = hl[(64 + lane) * HS + 4 * c + 2];
        float g3 = hl[(64 + lane) * HS + 4 * c + 3];
        const float* __restrict__ w = Wl + c * 256 + col0;
#pragma unroll
        for (int j = 0; j < 16; ++j) {
            float wa = w[j], wb = w[64 + j], wc = w[128 + j], wd = w[192 + j];
            s0[j] = fmaf(h0, wa, s0[j]);
            s0[j] = fmaf(h1, wb, s0[j]);
            s0[j] = fmaf(h2, wc, s0[j]);
            s0[j] = fmaf(h3, wd, s0[j]);
            s1[j] = fmaf(g0, wa, s1[j]);
            s1[j] = fmaf(g1, wb, s1[j]);
            s1[j] = fmaf(g2, wc, s1[j]);
            s1[j] = fmaf(g3, wd, s1[j]);
        }
    }
    if (act0) {
        float4* __restrict__ qp = (float4*)(Qout + (size_t)n0 * 128 + col0 * 2);
#pragma unroll
        for (int q = 0; q < 8; ++q)
            qp[q] = make_float4(a0[q * 2], s0[q * 2], a0[q * 2 + 1], s0[q * 2 + 1]);
    }
    if (act1) {
        float4* __restrict__ qp = (float4*)(Qout + (size_t)n1 * 128 + col0 * 2);
#pragma unroll
        for (int q = 0; q < 8; ++q)
            qp[q] = make_float4(a1[q * 2], s1[q * 2], a1[q * 2 + 1], s1[q * 2 + 1]);
    }
}

// ---------------------------------------------------------------------------
// Gate projections for one CGConv layer: P (src half, packed bf16) and
// Q (dst half + bias, fp32 (qf,qs) pairs).
// R14: R=2 nodes/thread (128-node tile), same rationale as premlp.
// ---------------------------------------------------------------------------
__global__ __launch_bounds__(256, 3) void pjq_kernel(
    const float* __restrict__ h,
    const float* __restrict__ Wf, const float* __restrict__ Ws,
    const float* __restrict__ bfv, const float* __restrict__ bsv,
    unsigned int* __restrict__ P, float* __restrict__ Q, int N)
{
    __shared__ __align__(16) float Wl[4096];
    __shared__ float hl[128 * HS];
    const int tid = threadIdx.x;
    const int lane = tid & 63;
    const int col0 = (tid >> 6) * 16;
    const int base = blockIdx.x * 128;
    const int n0 = base + lane;
    const int n1 = base + 64 + lane;
    const bool act0 = (n0 < N), act1 = (n1 < N);

    float a0[16], a1[16], s0[16], s1[16];

    // stage h tile (coalesced global read, padded LDS write) + WfS
    for (int q = tid; q < 2048; q += 256) {
        int r = q >> 4, c4 = q & 15;
        int rr = base + r; rr = (rr < N) ? rr : (N - 1);
        float4 v = ((const float4*)(h + (size_t)rr * 64))[c4];
        float* dp = hl + r * HS + c4 * 4;
        dp[0] = v.x; dp[1] = v.y; dp[2] = v.z; dp[3] = v.w;
    }
    {
        const float4* __restrict__ s4 = (const float4*)(Wf + 64 * 64);
        float4* __restrict__ d4 = (float4*)Wl;
        for (int i = tid; i < 1024; i += 256) d4[i] = s4[i];
    }
    __syncthreads();

    // ---- P-F ----
#pragma unroll
    for (int j = 0; j < 16; ++j) { a0[j] = 0.f; a1[j] = 0.f; }
    for (int c = 0; c < 16; ++c) {
        float h0 = hl[lane * HS + 4 * c + 0];
        float h1 = hl[lane * HS + 4 * c + 1];
        float h2 = hl[lane * HS + 4 * c + 2];
        float h3 = hl[lane * HS + 4 * c + 3];
        float g0 = hl[(64 + lane) * HS + 4 * c + 0];
        float g1 = hl[(64 + lane) * HS + 4 * c + 1];
        float g2 = hl[(64 + lane) * HS + 4 * c + 2];
        float g3 = hl[(64 + lane) * HS + 4 * c + 3];
        const float* __restrict__ w = Wl + c * 256 + col0;
#pragma unroll
        for (int j = 0; j < 16; ++j) {
            float wa = w[j], wb = w[64 + j], wc = w[128 + j], wd = w[192 + j];
            a0[j] = fmaf(h0, wa, a0[j]);
            a0[j] = fmaf(h1, wb, a0[j]);
            a0[j] = fmaf(h2, wc, a0[j]);
            a0[j] = fmaf(h3, wd, a0[j]);
            a1[j] = fmaf(g0, wa, a1[j]);
            a1[j] = fmaf(g1, wb, a1[j]);
            a1[j] = fmaf(g2, wc, a1[j]);
            a1[j] = fmaf(g3, wd, a1[j]);
        }
    }
    __syncthreads();
    {
        const float4* __restrict__ s4 = (const float4*)(Ws + 64 * 64);
        float4* __restrict__ d4 = (float4*)Wl;
        for (int i = tid; i < 1024; i += 256) d4[i] = s4[i];
    }
    __syncthreads();

    // ---- P-S + store ----
#pragma unroll
    for (int j = 0; j < 16; ++j) { s0[j] = 0.f; s1[j] = 0.f; }
    for (int c = 0; c < 16; ++c) {
        float h0 = hl[lane * HS + 4 * c + 0];
        float h1 = hl[lane * HS + 4 * c + 1];
        float h2 = hl[lane * HS + 4 * c + 2];
        float h3 = hl[lane * HS + 4 * c + 3];
        float g0 = hl[(64 + lane) * HS + 4 * c + 0];
        float g1 = hl[(64 + lane) * HS + 4 * c + 1];
        float g2 = hl[(64 + lane) * HS + 4 * c + 2];
        float g3 = hl[(64 + lane) * HS + 4 * c + 3];
        const float* __restrict__ w = Wl + c * 256 + col0;
#pragma unroll
        for (int j = 0; j < 16; ++j) {
            float wa = w[j], wb = w[64 + j], wc = w[128 + j], wd = w[192 + j];
            s0[j] = fmaf(h0, wa, s0[j]);
            s0[j] = fmaf(h1, wb, s0[j]);
            s0[j] = fmaf(h2, wc, s0[j]);
            s0[j] = fmaf(h3, wd, s0[j]);
            s1[j] = fmaf(g0, wa, s1[j]);
            s1[j] = fmaf(g1, wb, s1[j]);
            s1[j] = fmaf(g2, wc, s1[j]);
            s1[j] = fmaf(g3, wd, s1[j]);
        }
    }
    if (act0) {
        uint4* __restrict__ pp = (uint4*)(P + (size_t)n0 * 64 + col0);
#pragma unroll
        for (int q = 0; q < 4; ++q) {
            uint4 pk;
            pk.x = f2bf_rne(a0[q * 4])     | (f2bf_rne(s0[q * 4]) << 16);
            pk.y = f2bf_rne(a0[q * 4 + 1]) | (f2bf_rne(s0[q * 4 + 1]) << 16);
            pk.z = f2bf_rne(a0[q * 4 + 2]) | (f2bf_rne(s0[q * 4 + 2]) << 16);
            pk.w = f2bf_rne(a0[q * 4 + 3]) | (f2bf_rne(s0[q * 4 + 3]) << 16);
            pp[q] = pk;
        }
    }
    if (act1) {
        uint4* __restrict__ pp = (uint4*)(P + (size_t)n1 * 64 + col0);
#pragma unroll
        for (int q = 0; q < 4; ++q) {
            uint4 pk;
            pk.x = f2bf_rne(a1[q * 4])     | (f2bf_rne(s1[q * 4]) << 16);
            pk.y = f2bf_rne(a1[q * 4 + 1]) | (f2bf_rne(s1[q * 4 + 1]) << 16);
            pk.z = f2bf_rne(a1[q * 4 + 2]) | (f2bf_rne(s1[q * 4 + 2]) << 16);
            pk.w = f2bf_rne(a1[q * 4 + 3]) | (f2bf_rne(s1[q * 4 + 3]) << 16);
            pp[q] = pk;
        }
    }
    __syncthreads();
    {
        const float4* __restrict__ s4 = (const float4*)Wf;
        float4* __restrict__ d4 = (float4*)Wl;
        for (int i = tid; i < 1024; i += 256) d4[i] = s4[i];
    }
    __syncthreads();

    // ---- Q-F ----
#pragma unroll
    for (int j = 0; j < 16; ++j) { a0[j] = bfv[col0 + j]; a1[j] = a0[j]; }
    for (int c = 0; c < 16; ++c) {
        float h0 = hl[lane * HS + 4 * c + 0];
        float h1 = hl[lane * HS + 4 * c + 1];
        float h2 = hl[lane * HS + 4 * c + 2];
        float h3 = hl[lane * HS + 4 * c + 3];
        float g0 = hl[(64 + lane) * HS + 4 * c + 0];
        float g1 = hl[(64 + lane) * HS + 4 * c + 1];
        float g2 = hl[(64 + lane) * HS + 4 * c + 2];
        float g3 = hl[(64 + lane) * HS + 4 * c + 3];
        const float* __restrict__ w = Wl + c * 256 + col0;
#pragma unroll
        for (int j = 0; j < 16; ++j) {
            float wa = w[j], wb = w[64 + j], wc = w[128 + j], wd = w[192 + j];
            a0[j] = fmaf(h0, wa, a0[j]);
            a0[j] = fmaf(h1, wb, a0[j]);
            a0[j] = fmaf(h2, wc, a0[j]);
            a0[j] = fmaf(h3, wd, a0[j]);
            a1[j] = fmaf(g0, wa, a1[j]);
            a1[j] = fmaf(g1, wb, a1[j]);
            a1[j] = fmaf(g2, wc, a1[j]);
            a1[j] = fmaf(g3, wd, a1[j]);
        }
    }
    __syncthreads();
    {
        const float4* __restrict__ s4 = (const float4*)Ws;
        float4* __restrict__ d4 = (float4*)Wl;
        for (int i = tid; i < 1024; i += 256) d4[i] = s4[i];
    }
    __syncthreads();

    // ---- Q-S + store ----
#pragma unroll
    for (int j = 0; j < 16; ++j) { s0[j] = bsv[col0 + j]; s1[j] = s0[j]; }
    for (int c = 0; c < 16; ++c) {
        float h0 = hl[lane * HS + 4 * c + 0];
        float h1 = hl[lane * HS + 4 * c + 1];
        float h2 = hl[lane * HS + 4 * c + 2];
        float h3 = hl[lane * HS + 4 * c + 3];
        float g0 = hl[(64 + lane) * HS + 4 * c + 0];
        float g1 = hl[(64 + lane) * HS + 4 * c + 1];
        float g2 = hl[(64 + lane) * HS + 4 * c + 2];
        float g3 = hl[(64 + lane) * HS + 4 * c + 3];
        const float* __restrict__ w = Wl + c * 256 + col0;
#pragma unroll
        for (int j = 0; j < 16; ++j) {
            float wa = w[j], wb = w[64 + j], wc = w[128 + j], wd = w[192 + j];
            s0[j] = fmaf(h0, wa, s0[j]);
            s0[j] = fmaf(h1, wb, s0[j]);
            s0[j] = fmaf(h2, wc, s0[j]);
            s0[j] = fmaf(h3, wd, s0[j]);
            s1[j] = fmaf(g0, wa, s1[j]);
            s1[j] = fmaf(g1, wb, s1[j]);
            s1[j] = fmaf(g2, wc, s1[j]);
            s1[j] = fmaf(g3, wd, s1[j]);
        }
    }
    if (act0) {
        float4* __restrict__ qp = (float4*)(Q + (size_t)n0 * 128 + col0 * 2);
#pragma unroll
        for (int q = 0; q < 8; ++q)
            qp[q] = make_float4(a0[q * 2], s0[q * 2], a0[q * 2 + 1], s0[q * 2 + 1]);
    }
    if (act1) {
        float4* __restrict__ qp = (float4*)(Q + (size_t)n1 * 128 + col0 * 2);
#pragma unroll
        for (int q = 0; q < 8; ++q)
            qp[q] = make_float4(a1[q * 2], s1[q * 2], a1[q * 2 + 1], s1[q * 2 + 1]);
    }
}

// ---------------------------------------------------------------------------
// In-degree histogram (int)
// ---------------------------------------------------------------------------
__global__ __launch_bounds__(256) void deg_kernel(
    const int* __restrict__ dst, int* __restrict__ deg, int E)
{
    int e = blockIdx.x * blockDim.x + threadIdx.x;
    if (e < E) atomicAdd(&deg[dst[e]], 1);
}

// ---------------------------------------------------------------------------
// Three-phase exclusive scan over deg -> rowptr, cursor
// ---------------------------------------------------------------------------
__global__ __launch_bounds__(1024) void scanA_kernel(
    const int* __restrict__ deg, int* __restrict__ iscan,
    int* __restrict__ bsum, int N)
{
    __shared__ int lds[1024];
    int tid = threadIdx.x;
    int gid = blockIdx.x * 1024 + tid;
    int v = (gid < N) ? deg[gid] : 0;
    lds[tid] = v; __syncthreads();
    for (int off = 1; off < 1024; off <<= 1) {
        int t = (tid >= off) ? lds[tid - off] : 0;
        __syncthreads();
        lds[tid] += t;
        __syncthreads();
    }
    if (gid < N) iscan[gid] = lds[tid];
    if (tid == 1023) bsum[blockIdx.x] = lds[1023];
}

__global__ __launch_bounds__(128) void scanB_kernel(
    const int* __restrict__ bsum, int* __restrict__ boff, int nb)
{
    __shared__ int lds[128];
    int t = threadIdx.x;
    int v = (t < nb) ? bsum[t] : 0;
    lds[t] = v; __syncthreads();
    for (int off = 1; off < 128; off <<= 1) {
        int u = (t >= off) ? lds[t - off] : 0;
        __syncthreads();
        lds[t] += u;
        __syncthreads();
    }
    if (t < nb) boff[t] = lds[t] - v;  // exclusive
}

__global__ __launch_bounds__(256) void scanC_kernel(
    const int* __restrict__ iscan, const int* __restrict__ boff,
    const int* __restrict__ deg,
    int* __restrict__ rowptr, int* __restrict__ cursor, int N)
{
    int i = blockIdx.x * blockDim.x + threadIdx.x;
    if (i >= N) return;
    int incl = iscan[i] + boff[i >> 10];
    rowptr[i + 1] = incl;
    cursor[i] = incl - deg[i];
    if (i == 0) rowptr[0] = 0;
}

// ---------------------------------------------------------------------------
// Edge scatter into CSR order, packed (src, ea) int2
// ---------------------------------------------------------------------------
__global__ __launch_bounds__(256) void escatter_kernel(
    const int* __restrict__ src, const int* __restrict__ dst,
    const float* __restrict__ ea, int* __restrict__ cursor,
    int2* __restrict__ e_se, int E)
{
    int e = blockIdx.x * blockDim.x + threadIdx.x;
    if (e >= E) return;
    int pos = atomicAdd(&cursor[dst[e]], 1);
    e_se[pos] = make_int2(src[e], __float_as_int(ea[e]));
}

// ---------------------------------------------------------------------------
// CGConv edge pass. One wave per node, lane = dim. Q precomputed (R12).
// ---------------------------------------------------------------------------
__global__ __launch_bounds__(256) void edge_kernel(
    const float* __restrict__ h, const int* __restrict__ rowptr,
    const int2* __restrict__ e_se,
    const unsigned int* __restrict__ P,
    const float* __restrict__ Q,
    const float* __restrict__ Wf, const float* __restrict__ Ws,
    float* __restrict__ hout)
{
    int n = blockIdx.x * 4 + (threadIdx.x >> 6);   // grid exactly covers GN
    int d = threadIdx.x & 63;

    const float2 qv = ((const float2*)Q)[(size_t)n * 64 + d];
    float qf = qv.x, qs = qv.y;
    float wf = Wf[128 * 64 + d];
    float ws = Ws[128 * 64 + d];

    size_t idx = (size_t)n * 64 + d;
    float hres = h[idx];

    int rb = rowptr[n], re = rowptr[n + 1];
    float agg = 0.f;
#pragma unroll 8
    for (int p = rb; p < re; ++p) {
        int2 se = e_se[p];         // wave-uniform 8B load
        int s = se.x;
        float ea = __int_as_float(se.y);
        unsigned int pv = P[(size_t)s * 64 + d];   // gathered dword (256B/wave)
        float pf = __uint_as_float(pv << 16);
        float psv = __uint_as_float(pv & 0xffff0000u);
        float xF = fmaf(ea, wf, qf + pf);
        float xS = fmaf(ea, ws, qs + psv);
        float sig = __builtin_amdgcn_rcpf(1.f + __expf(-xF));
        float t = __expf(-fabsf(xS));
        float sp = fmaxf(xS, 0.f) + __logf(1.f + t);
        agg = fmaf(sig, sp, agg);
    }

    float inv = 1.f / (float)max(re - rb, 1);
    hout[idx] = fmaxf(hres + agg * inv, 0.f);
}

// ---------------------------------------------------------------------------
// Graph segment starts: bm sorted; gstart[b] = first node of graph b.
// ---------------------------------------------------------------------------
__global__ __launch_bounds__(256) void gstart_kernel(
    const int* __restrict__ bm, int* __restrict__ gstart, int N)
{
    int i = blockIdx.x * blockDim.x + threadIdx.x;
    if (i >= N) return;
    int b = bm[i];
    int prev = (i == 0) ? -1 : bm[i - 1];
    for (int g = prev + 1; g <= b; ++g) gstart[g] = i;
    if (i == N - 1)
        for (int g = b + 1; g <= GB; ++g) gstart[g] = N;
}

// ---------------------------------------------------------------------------
// Segmented mean pool: one block per graph, no atomics.
// ---------------------------------------------------------------------------
__global__ __launch_bounds__(256) void pool_seg_kernel(
    const float* __restrict__ h, const int* __restrict__ gstart,
    float* __restrict__ g)
{
    int b = blockIdx.x;
    int s = gstart[b], e = gstart[b + 1];
    int d = threadIdx.x & 63;
    int w = threadIdx.x >> 6;
    float acc = 0.f;
    for (int n = s + w; n < e; n += 4)
        acc += h[(size_t)n * 64 + d];
    __shared__ float lds[256];
    lds[threadIdx.x] = acc;
    __syncthreads();
    if (w == 0) {
        acc = lds[d] + lds[64 + d] + lds[128 + d] + lds[192 + d];
        g[b * 64 + d] = acc / fmaxf((float)(e - s), 1.f);
    }
}

// ---------------------------------------------------------------------------
// Fused post-MLP (3 relu layers) + final dot + bias. One wave per graph.
// ---------------------------------------------------------------------------
__global__ __launch_bounds__(256) void postmlp_kernel(
    const float* __restrict__ g,
    const float* __restrict__ W0, const float* __restrict__ b0,
    const float* __restrict__ W1, const float* __restrict__ b1,
    const float* __restrict__ W2, const float* __restrict__ b2,
    const float* __restrict__ Wfin, const float* __restrict__ bfin,
    float* __restrict__ out)
{
    int b = blockIdx.x * 4 + (threadIdx.x >> 6);   // 32 blocks x 4 waves = 128
    int d = threadIdx.x & 63;
    float h = g[(size_t)b * 64 + d];

    float acc = b0[d];
#pragma unroll
    for (int k = 0; k < 64; ++k)
        acc = fmaf(__shfl(h, k, 64), W0[k * 64 + d], acc);
    h = fmaxf(acc, 0.f);

    acc = b1[d];
#pragma unroll
    for (int k = 0; k < 64; ++k)
        acc = fmaf(__shfl(h, k, 64), W1[k * 64 + d], acc);
    h = fmaxf(acc, 0.f);

    acc = b2[d];
#pragma unroll
    for (int k = 0; k < 64; ++k)
        acc = fmaf(__shfl(h, k, 64), W2[k * 64 + d], acc);
    h = fmaxf(acc, 0.f);

    float v = h * Wfin[d];
#pragma unroll
    for (int off = 32; off >= 1; off >>= 1)
        v += __shfl_xor(v, off, 64);
    if (d == 0) out[b] = v + bfin[0];
}

extern "C" void kernel_launch(void* const* d_in, const int* in_sizes, int n_in,
                              void* d_out, int out_size, void* d_ws, size_t ws_size,
                              hipStream_t stream)
{
    const float* X      = (const float*)d_in[0];
    const int*   eidx   = (const int*)d_in[1];
    const float* ea     = (const float*)d_in[3];
    const int*   bm     = (const int*)d_in[4];
    const float* pre_W0 = (const float*)d_in[5];
    const float* pre_b0 = (const float*)d_in[6];
    const float* pre_W1 = (const float*)d_in[7];
    const float* pre_b1 = (const float*)d_in[8];
    const float* pre_W2 = (const float*)d_in[9];
    const float* pre_b2 = (const float*)d_in[10];
    const float* cg_Wf  = (const float*)d_in[11];
    const float* cg_bf  = (const float*)d_in[12];
    const float* cg_Ws  = (const float*)d_in[13];
    const float* cg_bs  = (const float*)d_in[14];
    const float* post_W0 = (const float*)d_in[15];
    const float* post_b0 = (const float*)d_in[16];
    const float* post_W1 = (const float*)d_in[17];
    const float* post_b1 = (const float*)d_in[18];
    const float* post_W2 = (const float*)d_in[19];
    const float* post_b2 = (const float*)d_in[20];
    const float* post_Wf = (const float*)d_in[21];
    const float* post_bf = (const float*)d_in[22];

    const int* src = eidx;
    const int* dst = eidx + GE;

    // ---- workspace carve-up ----
    const size_t N64 = (size_t)GN * 64;
    float* hA    = (float*)d_ws;            // N*64
    float* hB    = hA + N64;                // N*64
    unsigned int* P = (unsigned int*)(hB + N64);  // N*64 packed bf16x2
    int* deg_i   = (int*)(P + N64);         // N
    int* iscan   = deg_i + GN;              // N
    int* bsum    = iscan + GN;              // 128
    int* boff    = bsum + 128;              // 128
    int* rowptr  = boff + 128;              // N+2 (padded so e_se is 8B-aligned)
    int* cursor  = rowptr + GN + 2;         // N
    int2* e_se   = (int2*)(cursor + GN);    // E int2 (8B-aligned)
    int* gstart  = (int*)(e_se + GE);       // B+1
    float* g0    = (float*)(gstart + GB + 1); // B*64 (8192 floats, keeps 8B align)
    float* Q     = g0 + (size_t)GB * 64;    // N*128 fp32 (qf,qs) pairs

    const int TPB = 256;
    int gridE  = (GE + TPB - 1) / TPB;
    int gridN  = (GN + TPB - 1) / TPB;         // 391 (lane=node grid)
    int gridP  = (GN + 127) / 128;             // 782 (R=2 col-split dense grid)
    int gridND = ((GN * 64) + TPB - 1) / TPB;  // 25000 (edge grid)
    int scanBlocks = (GN + 1023) / 1024;       // 98

    // per-layer weight pointers
    const float* Wf0 = cg_Wf;
    const float* Ws0 = cg_Ws;
    const float* Wf1 = cg_Wf + (size_t)1 * GZ * GD;
    const float* Ws1 = cg_Ws + (size_t)1 * GZ * GD;
    const float* Wf2 = cg_Wf + (size_t)2 * GZ * GD;
    const float* Ws2 = cg_Ws + (size_t)2 * GZ * GD;

    // fused pre-MLP (col-split, R=2) + P0 + Q0
    premlp_kernel<<<gridP, TPB, 0, stream>>>(
        X, pre_W0, pre_b0, pre_W1, pre_b1, pre_W2, pre_b2,
        Wf0, Ws0, Wf0 + 64 * 64, Ws0 + 64 * 64, cg_bf, cg_bs,
        hA, P, Q, GN);

    // degree + CSR build
    hipMemsetAsync(deg_i, 0, GN * sizeof(int), stream);
    deg_kernel<<<gridE, TPB, 0, stream>>>(dst, deg_i, GE);
    scanA_kernel<<<scanBlocks, 1024, 0, stream>>>(deg_i, iscan, bsum, GN);
    scanB_kernel<<<1, 128, 0, stream>>>(bsum, boff, scanBlocks);
    scanC_kernel<<<gridN, TPB, 0, stream>>>(iscan, boff, deg_i, rowptr, cursor, GN);
    escatter_kernel<<<gridE, TPB, 0, stream>>>(src, dst, ea, cursor, e_se, GE);

    // graph segment starts (bm sorted)
    gstart_kernel<<<gridN, TPB, 0, stream>>>(bm, gstart, GN);

    // CGConv layers: lean edge pass + fused P/Q projection for next layer
    edge_kernel<<<gridND, TPB, 0, stream>>>(
        hA, rowptr, e_se, P, Q, Wf0, Ws0, hB);
    pjq_kernel<<<gridP, TPB, 0, stream>>>(
        hB, Wf1, Ws1, cg_bf + GD, cg_bs + GD, P, Q, GN);
    edge_kernel<<<gridND, TPB, 0, stream>>>(
        hB, rowptr, e_se, P, Q, Wf1, Ws1, hA);
    pjq_kernel<<<gridP, TPB, 0, stream>>>(
        hA, Wf2, Ws2, cg_bf + 2 * GD, cg_bs + 2 * GD, P, Q, GN);
    edge_kernel<<<gridND, TPB, 0, stream>>>(
        hA, rowptr, e_se, P, Q, Wf2, Ws2, hB);

    // segmented mean pool (no atomics)
    pool_seg_kernel<<<GB, TPB, 0, stream>>>(hB, gstart, g0);

    // fused post-MLP + final projection
    postmlp_kernel<<<GB / 4, TPB, 0, stream>>>(
        g0, post_W0, post_b0, post_W1, post_b1, post_W2, post_b2,
        post_Wf, post_bf, (float*)d_out);
}